// Round 4
// baseline (650.461 us; speedup 1.0000x reference)
//
#include <hip/hip_runtime.h>

// GCN 2-layer + FC. Round 4: grid-fused {CSR fill | GEMM1} (independent work,
// disjoint pipes -> max instead of sum), gather64+FC fused with wave butterfly
// reduction, memset for deg zeroing. 9 launches total.

static constexpr int TPB = 256;

// ---------- CSR build ----------
__global__ __launch_bounds__(256) void k_deg_count(const int* __restrict__ dst,
                                                   int* __restrict__ deg, int E) {
    int e = blockIdx.x * blockDim.x + threadIdx.x;
    if (e < E) atomicAdd(&deg[dst[e]], 1);
}

__global__ __launch_bounds__(256) void k_scan_partial(const int* __restrict__ deg,
                                                      int* __restrict__ bsum, int n) {
    __shared__ int lds[256];
    int i = blockIdx.x * 256 + threadIdx.x;
    lds[threadIdx.x] = (i < n) ? deg[i] : 0;
    __syncthreads();
    for (int off = 128; off > 0; off >>= 1) {
        if (threadIdx.x < off) lds[threadIdx.x] += lds[threadIdx.x + off];
        __syncthreads();
    }
    if (threadIdx.x == 0) bsum[blockIdx.x] = lds[0];
}

__global__ __launch_bounds__(512) void k_scan_bsums(const int* __restrict__ bsum,
                                                    int* __restrict__ boff, int nb) {
    __shared__ int lds[512];
    int t = threadIdx.x;
    int v = (t < nb) ? bsum[t] : 0;
    lds[t] = v;
    __syncthreads();
    for (int off = 1; off < 512; off <<= 1) {
        int add = (t >= off) ? lds[t - off] : 0;
        __syncthreads();
        lds[t] += add;
        __syncthreads();
    }
    if (t < nb) boff[t] = lds[t] - v;
}

__global__ __launch_bounds__(256) void k_scan_final(const int* __restrict__ deg,
                                                    const int* __restrict__ boff,
                                                    int* __restrict__ row_ptr,
                                                    int* __restrict__ cursor,
                                                    float* __restrict__ dinv, int n) {
    __shared__ int lds[256];
    int i = blockIdx.x * 256 + threadIdx.x;
    int v = (i < n) ? deg[i] : 0;
    lds[threadIdx.x] = v;
    __syncthreads();
    for (int off = 1; off < 256; off <<= 1) {
        int add = (threadIdx.x >= off) ? lds[threadIdx.x - off] : 0;
        __syncthreads();
        lds[threadIdx.x] += add;
        __syncthreads();
    }
    if (i < n) {
        int incl = lds[threadIdx.x];
        int rp = boff[blockIdx.x] + (incl - v);
        row_ptr[i] = rp;
        cursor[i]  = rp;
        dinv[i]    = rsqrtf((float)(v + 1));
        if (i == n - 1) row_ptr[n] = rp + v;
    }
}

// ---------- fused {fill | gemm1}: independent after scan_final ----------
// blocks [0, fillBlocks): grid-stride CSR fill (latency/atomic bound).
// blocks [fillBlocks, ...): GEMM1 H = (X@W1)*dinv, 4x8 micro-tile (VALU bound).
__global__ __launch_bounds__(256) void k_fill_gemm1(
        const int* __restrict__ src, const int* __restrict__ dst,
        int* __restrict__ cursor, int* __restrict__ col, int E,
        const float* __restrict__ X, const float* __restrict__ W,
        const float* __restrict__ dinv, float* __restrict__ H, int n,
        int fillBlocks) {
    if ((int)blockIdx.x < fillBlocks) {
        int stride = fillBlocks * 256;
        for (int e = blockIdx.x * 256 + threadIdx.x; e < E; e += stride) {
            int pos = atomicAdd(&cursor[dst[e]], 1);
            col[pos] = src[e];
        }
        return;
    }
    int bid = blockIdx.x - fillBlocks;
    int t = threadIdx.x;
    int tc = t & 15, tr = t >> 4;
    int c0 = tc * 8;
    int r0 = bid * 64 + tr * 4;

    const float* xp[4];
#pragma unroll
    for (int i = 0; i < 4; ++i) {
        int r = r0 + i;
        xp[i] = X + (size_t)(r < n ? r : 0) * 128;
    }
    float acc[4][8];
#pragma unroll
    for (int i = 0; i < 4; ++i)
#pragma unroll
        for (int j = 0; j < 8; ++j) acc[i][j] = 0.f;

    for (int k0 = 0; k0 < 128; k0 += 4) {
        float4 xv[4];
#pragma unroll
        for (int i = 0; i < 4; ++i) xv[i] = *(const float4*)(xp[i] + k0);
        float4 w0[4], w1[4];
#pragma unroll
        for (int kk = 0; kk < 4; ++kk) {
            const float* wr = W + (size_t)(k0 + kk) * 128 + c0;
            w0[kk] = *(const float4*)wr;
            w1[kk] = *(const float4*)(wr + 4);
        }
#pragma unroll
        for (int kk = 0; kk < 4; ++kk) {
            const float* wf0 = (const float*)&w0[kk];
            const float* wf1 = (const float*)&w1[kk];
#pragma unroll
            for (int i = 0; i < 4; ++i) {
                float xs = ((const float*)&xv[i])[kk];
#pragma unroll
                for (int j = 0; j < 4; ++j) {
                    acc[i][j]     = fmaf(xs, wf0[j], acc[i][j]);
                    acc[i][j + 4] = fmaf(xs, wf1[j], acc[i][j + 4]);
                }
            }
        }
    }
#pragma unroll
    for (int i = 0; i < 4; ++i) {
        int r = r0 + i;
        if (r >= n) continue;
        float s = dinv[r];
        float4 o0, o1;
        o0.x = acc[i][0] * s; o0.y = acc[i][1] * s; o0.z = acc[i][2] * s; o0.w = acc[i][3] * s;
        o1.x = acc[i][4] * s; o1.y = acc[i][5] * s; o1.z = acc[i][6] * s; o1.w = acc[i][7] * s;
        float* hr = H + (size_t)r * 128 + c0;
        *(float4*)hr = o0;
        *(float4*)(hr + 4) = o1;
    }
}

// ---------- GEMM2: H2 = (relu(B + b1) @ W2) * dinv; 4x8 micro-tile ----------
__global__ __launch_bounds__(256) void k_gemm2(const float* __restrict__ B,
                                               const float* __restrict__ W2,
                                               const float* __restrict__ b1,
                                               const float* __restrict__ dinv,
                                               float* __restrict__ H2, int n) {
    int t = threadIdx.x;
    int tc = t & 7, tr = t >> 3;
    int c0 = tc * 8;
    int r0 = blockIdx.x * 128 + tr * 4;

    const float* xp[4];
#pragma unroll
    for (int i = 0; i < 4; ++i) {
        int r = r0 + i;
        xp[i] = B + (size_t)(r < n ? r : 0) * 128;
    }
    float acc[4][8];
#pragma unroll
    for (int i = 0; i < 4; ++i)
#pragma unroll
        for (int j = 0; j < 8; ++j) acc[i][j] = 0.f;

    for (int k0 = 0; k0 < 128; k0 += 4) {
        float4 bb = *(const float4*)(b1 + k0);
        float4 xv[4];
#pragma unroll
        for (int i = 0; i < 4; ++i) {
            float4 v = *(const float4*)(xp[i] + k0);
            v.x = fmaxf(v.x + bb.x, 0.f);
            v.y = fmaxf(v.y + bb.y, 0.f);
            v.z = fmaxf(v.z + bb.z, 0.f);
            v.w = fmaxf(v.w + bb.w, 0.f);
            xv[i] = v;
        }
        float4 w0[4], w1[4];
#pragma unroll
        for (int kk = 0; kk < 4; ++kk) {
            const float* wr = W2 + (size_t)(k0 + kk) * 64 + c0;
            w0[kk] = *(const float4*)wr;
            w1[kk] = *(const float4*)(wr + 4);
        }
#pragma unroll
        for (int kk = 0; kk < 4; ++kk) {
            const float* wf0 = (const float*)&w0[kk];
            const float* wf1 = (const float*)&w1[kk];
#pragma unroll
            for (int i = 0; i < 4; ++i) {
                float xs = ((const float*)&xv[i])[kk];
#pragma unroll
                for (int j = 0; j < 4; ++j) {
                    acc[i][j]     = fmaf(xs, wf0[j], acc[i][j]);
                    acc[i][j + 4] = fmaf(xs, wf1[j], acc[i][j + 4]);
                }
            }
        }
    }
#pragma unroll
    for (int i = 0; i < 4; ++i) {
        int r = r0 + i;
        if (r >= n) continue;
        float s = dinv[r];
        float4 o0, o1;
        o0.x = acc[i][0] * s; o0.y = acc[i][1] * s; o0.z = acc[i][2] * s; o0.w = acc[i][3] * s;
        o1.x = acc[i][4] * s; o1.y = acc[i][5] * s; o1.z = acc[i][6] * s; o1.w = acc[i][7] * s;
        float* hr = H2 + (size_t)r * 64 + c0;
        *(float4*)hr = o0;
        *(float4*)(hr + 4) = o1;
    }
}

// ---------- layer-1 gather (128-d): out[d] = (H'[d] + sum H'[s]) * dinv[d] ----------
__global__ __launch_bounds__(256) void k_gather128(const float* __restrict__ Hs,
                                                   const float* __restrict__ dinv,
                                                   const int* __restrict__ row_ptr,
                                                   const int* __restrict__ col,
                                                   float* __restrict__ out, int n) {
    constexpr int VEC = 2, D = 128;
    int wave = threadIdx.x >> 6;
    int lane = threadIdx.x & 63;
    int node = blockIdx.x * 4 + wave;
    if (node >= n) return;
    int beg = row_ptr[node], end = row_ptr[node + 1];
    int deg = end - beg;

    float acc[VEC];
    const float* hr = Hs + (size_t)node * D + lane * VEC;
#pragma unroll
    for (int v = 0; v < VEC; ++v) acc[v] = hr[v];

    for (int base = 0; base < deg; base += 64) {
        int m = deg - base; if (m > 64) m = 64;
        int cl = (lane < m) ? col[beg + base + lane] : 0;
        int j = 0;
        for (; j + 4 <= m; j += 4) {
            int s0 = __shfl(cl, j + 0);
            int s1 = __shfl(cl, j + 1);
            int s2 = __shfl(cl, j + 2);
            int s3 = __shfl(cl, j + 3);
            const float* p0 = Hs + (size_t)s0 * D + lane * VEC;
            const float* p1 = Hs + (size_t)s1 * D + lane * VEC;
            const float* p2 = Hs + (size_t)s2 * D + lane * VEC;
            const float* p3 = Hs + (size_t)s3 * D + lane * VEC;
            float t0[VEC], t1[VEC], t2[VEC], t3[VEC];
#pragma unroll
            for (int v = 0; v < VEC; ++v) t0[v] = p0[v];
#pragma unroll
            for (int v = 0; v < VEC; ++v) t1[v] = p1[v];
#pragma unroll
            for (int v = 0; v < VEC; ++v) t2[v] = p2[v];
#pragma unroll
            for (int v = 0; v < VEC; ++v) t3[v] = p3[v];
#pragma unroll
            for (int v = 0; v < VEC; ++v)
                acc[v] += (t0[v] + t1[v]) + (t2[v] + t3[v]);
        }
        for (; j < m; ++j) {
            int s = __shfl(cl, j);
            const float* sr = Hs + (size_t)s * D + lane * VEC;
#pragma unroll
            for (int v = 0; v < VEC; ++v) acc[v] += sr[v];
        }
    }
    float dd = dinv[node];
    float* o = out + (size_t)node * D + lane * VEC;
#pragma unroll
    for (int v = 0; v < VEC; ++v) o[v] = acc[v] * dd;
}

// ---------- layer-2 gather (64-d) fused with FC head ----------
// lane c holds feature c. After aggregation: v = relu(acc*dinv + b2[c]);
// out[node][j] = sum_c v_c * Wfc[c][j] + bfc[j]  via __shfl_xor butterfly.
__global__ __launch_bounds__(256) void k_gather_fc(const float* __restrict__ Hs,
                                                   const float* __restrict__ dinv,
                                                   const int* __restrict__ row_ptr,
                                                   const int* __restrict__ col,
                                                   const float* __restrict__ b2,
                                                   const float* __restrict__ Wfc,
                                                   const float* __restrict__ bfc,
                                                   float* __restrict__ out, int n) {
    int wave = threadIdx.x >> 6;
    int lane = threadIdx.x & 63;
    float wrow[10];
#pragma unroll
    for (int j = 0; j < 10; ++j) wrow[j] = Wfc[lane * 10 + j];
    float b2c = b2[lane];

    int node = blockIdx.x * 4 + wave;
    if (node >= n) return;
    int beg = row_ptr[node], end = row_ptr[node + 1];
    int deg = end - beg;

    float acc = Hs[(size_t)node * 64 + lane];
    for (int base = 0; base < deg; base += 64) {
        int m = deg - base; if (m > 64) m = 64;
        int cl = (lane < m) ? col[beg + base + lane] : 0;
        int j = 0;
        for (; j + 4 <= m; j += 4) {
            int s0 = __shfl(cl, j + 0);
            int s1 = __shfl(cl, j + 1);
            int s2 = __shfl(cl, j + 2);
            int s3 = __shfl(cl, j + 3);
            float t0 = Hs[(size_t)s0 * 64 + lane];
            float t1 = Hs[(size_t)s1 * 64 + lane];
            float t2 = Hs[(size_t)s2 * 64 + lane];
            float t3 = Hs[(size_t)s3 * 64 + lane];
            acc += (t0 + t1) + (t2 + t3);
        }
        for (; j < m; ++j) {
            int s = __shfl(cl, j);
            acc += Hs[(size_t)s * 64 + lane];
        }
    }
    float v = fmaxf(acc * dinv[node] + b2c, 0.f);
    float p[10];
#pragma unroll
    for (int j = 0; j < 10; ++j) p[j] = v * wrow[j];
#pragma unroll
    for (int off = 32; off > 0; off >>= 1)
#pragma unroll
        for (int j = 0; j < 10; ++j) p[j] += __shfl_xor(p[j], off);
    if (lane == 0) {
        float* o = out + (size_t)node * 10;
#pragma unroll
        for (int j = 0; j < 10; ++j) o[j] = p[j] + bfc[j];
    }
}

static inline int cdiv(long long a, int b) { return (int)((a + b - 1) / b); }

extern "C" void kernel_launch(void* const* d_in, const int* in_sizes, int n_in,
                              void* d_out, int out_size, void* d_ws, size_t ws_size,
                              hipStream_t stream) {
    const float* x   = (const float*)d_in[0];
    const int*   ei  = (const int*)d_in[1];
    const float* W1  = (const float*)d_in[2];
    const float* b1  = (const float*)d_in[3];
    const float* W2  = (const float*)d_in[4];
    const float* b2  = (const float*)d_in[5];
    const float* Wfc = (const float*)d_in[6];
    const float* bfc = (const float*)d_in[7];
    float* out = (float*)d_out;

    const int N = in_sizes[0] / 128;   // 100000
    const int E = in_sizes[1] / 2;     // 1600000
    const int* src = ei;
    const int* dst = ei + E;
    const int nb = cdiv(N, 256);       // 391

    char* ws = (char*)d_ws;
    size_t off = 0;
    auto alloc = [&](size_t bytes) { void* p = ws + off; off = (off + bytes + 255) & ~(size_t)255; return p; };
    float* dinv    = (float*)alloc((size_t)N * 4);
    int*   deg     = (int*)  alloc((size_t)N * 4);
    int*   row_ptr = (int*)  alloc((size_t)(N + 1) * 4);
    int*   cursor  = (int*)  alloc((size_t)N * 4);
    int*   bsum    = (int*)  alloc(512 * 4);
    int*   boff    = (int*)  alloc(512 * 4);
    int*   col     = (int*)  alloc((size_t)E * 4);
    float* bufA    = (float*)alloc((size_t)N * 128 * 4);
    float* bufB    = (float*)alloc((size_t)N * 128 * 4);

    // CSR build
    hipMemsetAsync(deg, 0, (size_t)N * 4, stream);
    k_deg_count<<<cdiv(E, TPB), TPB, 0, stream>>>(dst, deg, E);
    k_scan_partial<<<nb, 256, 0, stream>>>(deg, bsum, N);
    k_scan_bsums<<<1, 512, 0, stream>>>(bsum, boff, nb);
    k_scan_final<<<nb, 256, 0, stream>>>(deg, boff, row_ptr, cursor, dinv, N);

    // fused: CSR fill (blocks [0,1024)) | GEMM1 (blocks [1024, 1024+N/64))
    const int fillBlocks = 1024;
    k_fill_gemm1<<<fillBlocks + cdiv(N, 64), 256, 0, stream>>>(
        src, dst, cursor, col, E, x, W1, dinv, bufA, N, fillBlocks);

    // layer 1 aggregate
    k_gather128<<<cdiv(N, 4), 256, 0, stream>>>(bufA, dinv, row_ptr, col, bufB, N);

    // layer 2 transform then aggregate+FC (writes d_out directly)
    k_gemm2<<<cdiv(N, 128), 256, 0, stream>>>(bufB, W2, b1, dinv, bufA, N);
    k_gather_fc<<<cdiv(N, 4), 256, 0, stream>>>(bufA, dinv, row_ptr, col,
                                                b2, Wfc, bfc, out, N);
}

// Round 5
// 607.000 us; speedup vs baseline: 1.0716x; 1.0716x over previous
//
#include <hip/hip_runtime.h>

// GCN 2-layer + FC. Round 5: interleaved {fill|GEMM1} grid roles (co-resident
// overlap), half-wave float4 gathers (2 edges in flight per load inst for
// 128-d, 4 edges for 64-d), gather64+FC fused.

static constexpr int TPB = 256;

// ---------- CSR build ----------
__global__ __launch_bounds__(256) void k_deg_count(const int* __restrict__ dst,
                                                   int* __restrict__ deg, int E) {
    int e = blockIdx.x * blockDim.x + threadIdx.x;
    if (e < E) atomicAdd(&deg[dst[e]], 1);
}

__global__ __launch_bounds__(256) void k_scan_partial(const int* __restrict__ deg,
                                                      int* __restrict__ bsum, int n) {
    __shared__ int lds[256];
    int i = blockIdx.x * 256 + threadIdx.x;
    lds[threadIdx.x] = (i < n) ? deg[i] : 0;
    __syncthreads();
    for (int off = 128; off > 0; off >>= 1) {
        if (threadIdx.x < off) lds[threadIdx.x] += lds[threadIdx.x + off];
        __syncthreads();
    }
    if (threadIdx.x == 0) bsum[blockIdx.x] = lds[0];
}

__global__ __launch_bounds__(512) void k_scan_bsums(const int* __restrict__ bsum,
                                                    int* __restrict__ boff, int nb) {
    __shared__ int lds[512];
    int t = threadIdx.x;
    int v = (t < nb) ? bsum[t] : 0;
    lds[t] = v;
    __syncthreads();
    for (int off = 1; off < 512; off <<= 1) {
        int add = (t >= off) ? lds[t - off] : 0;
        __syncthreads();
        lds[t] += add;
        __syncthreads();
    }
    if (t < nb) boff[t] = lds[t] - v;
}

__global__ __launch_bounds__(256) void k_scan_final(const int* __restrict__ deg,
                                                    const int* __restrict__ boff,
                                                    int* __restrict__ row_ptr,
                                                    int* __restrict__ cursor,
                                                    float* __restrict__ dinv, int n) {
    __shared__ int lds[256];
    int i = blockIdx.x * 256 + threadIdx.x;
    int v = (i < n) ? deg[i] : 0;
    lds[threadIdx.x] = v;
    __syncthreads();
    for (int off = 1; off < 256; off <<= 1) {
        int add = (threadIdx.x >= off) ? lds[threadIdx.x - off] : 0;
        __syncthreads();
        lds[threadIdx.x] += add;
        __syncthreads();
    }
    if (i < n) {
        int incl = lds[threadIdx.x];
        int rp = boff[blockIdx.x] + (incl - v);
        row_ptr[i] = rp;
        cursor[i]  = rp;
        dinv[i]    = rsqrtf((float)(v + 1));
        if (i == n - 1) row_ptr[n] = rp + v;
    }
}

// ---------- interleaved {fill | gemm1} ----------
// blockIdx % 5 < 2 -> CSR fill role (grid-stride over edges);
// else             -> GEMM1 role: H = (X@W1)*dinv, 4x8 micro-tile.
// Interleaving keeps both roles co-resident on every CU from t=0.
__global__ __launch_bounds__(256) void k_fill_gemm1(
        const int* __restrict__ src, const int* __restrict__ dst,
        int* __restrict__ cursor, int* __restrict__ col, int E,
        const float* __restrict__ X, const float* __restrict__ W,
        const float* __restrict__ dinv, float* __restrict__ H, int n,
        int nFill) {
    int q = blockIdx.x / 5, r5 = blockIdx.x % 5;
    if (r5 < 2) {
        int fid = q * 2 + r5;                 // 0 .. nFill-1
        int stride = nFill * 256;
        for (int e = fid * 256 + threadIdx.x; e < E; e += stride) {
            int pos = atomicAdd(&cursor[dst[e]], 1);
            col[pos] = src[e];
        }
        return;
    }
    int bid = q * 3 + (r5 - 2);               // GEMM block id
    int t = threadIdx.x;
    int tc = t & 15, tr = t >> 4;
    int c0 = tc * 8;
    int r0 = bid * 64 + tr * 4;
    if (r0 >= n + 3 && r0 >= n) { /* fallthrough guarded below */ }

    const float* xp[4];
#pragma unroll
    for (int i = 0; i < 4; ++i) {
        int rr = r0 + i;
        xp[i] = X + (size_t)(rr < n ? rr : 0) * 128;
    }
    float acc[4][8];
#pragma unroll
    for (int i = 0; i < 4; ++i)
#pragma unroll
        for (int j = 0; j < 8; ++j) acc[i][j] = 0.f;

    for (int k0 = 0; k0 < 128; k0 += 4) {
        float4 xv[4];
#pragma unroll
        for (int i = 0; i < 4; ++i) xv[i] = *(const float4*)(xp[i] + k0);
        float4 w0[4], w1[4];
#pragma unroll
        for (int kk = 0; kk < 4; ++kk) {
            const float* wr = W + (size_t)(k0 + kk) * 128 + c0;
            w0[kk] = *(const float4*)wr;
            w1[kk] = *(const float4*)(wr + 4);
        }
#pragma unroll
        for (int kk = 0; kk < 4; ++kk) {
            const float* wf0 = (const float*)&w0[kk];
            const float* wf1 = (const float*)&w1[kk];
#pragma unroll
            for (int i = 0; i < 4; ++i) {
                float xs = ((const float*)&xv[i])[kk];
#pragma unroll
                for (int j = 0; j < 4; ++j) {
                    acc[i][j]     = fmaf(xs, wf0[j], acc[i][j]);
                    acc[i][j + 4] = fmaf(xs, wf1[j], acc[i][j + 4]);
                }
            }
        }
    }
#pragma unroll
    for (int i = 0; i < 4; ++i) {
        int rr = r0 + i;
        if (rr >= n) continue;
        float s = dinv[rr];
        float4 o0, o1;
        o0.x = acc[i][0] * s; o0.y = acc[i][1] * s; o0.z = acc[i][2] * s; o0.w = acc[i][3] * s;
        o1.x = acc[i][4] * s; o1.y = acc[i][5] * s; o1.z = acc[i][6] * s; o1.w = acc[i][7] * s;
        float* hr = H + (size_t)rr * 128 + c0;
        *(float4*)hr = o0;
        *(float4*)(hr + 4) = o1;
    }
}

// ---------- GEMM2: H2 = (relu(B + b1) @ W2) * dinv; 4x8 micro-tile ----------
__global__ __launch_bounds__(256) void k_gemm2(const float* __restrict__ B,
                                               const float* __restrict__ W2,
                                               const float* __restrict__ b1,
                                               const float* __restrict__ dinv,
                                               float* __restrict__ H2, int n) {
    int t = threadIdx.x;
    int tc = t & 7, tr = t >> 3;
    int c0 = tc * 8;
    int r0 = blockIdx.x * 128 + tr * 4;

    const float* xp[4];
#pragma unroll
    for (int i = 0; i < 4; ++i) {
        int r = r0 + i;
        xp[i] = B + (size_t)(r < n ? r : 0) * 128;
    }
    float acc[4][8];
#pragma unroll
    for (int i = 0; i < 4; ++i)
#pragma unroll
        for (int j = 0; j < 8; ++j) acc[i][j] = 0.f;

    for (int k0 = 0; k0 < 128; k0 += 4) {
        float4 bb = *(const float4*)(b1 + k0);
        float4 xv[4];
#pragma unroll
        for (int i = 0; i < 4; ++i) {
            float4 v = *(const float4*)(xp[i] + k0);
            v.x = fmaxf(v.x + bb.x, 0.f);
            v.y = fmaxf(v.y + bb.y, 0.f);
            v.z = fmaxf(v.z + bb.z, 0.f);
            v.w = fmaxf(v.w + bb.w, 0.f);
            xv[i] = v;
        }
        float4 w0[4], w1[4];
#pragma unroll
        for (int kk = 0; kk < 4; ++kk) {
            const float* wr = W2 + (size_t)(k0 + kk) * 64 + c0;
            w0[kk] = *(const float4*)wr;
            w1[kk] = *(const float4*)(wr + 4);
        }
#pragma unroll
        for (int kk = 0; kk < 4; ++kk) {
            const float* wf0 = (const float*)&w0[kk];
            const float* wf1 = (const float*)&w1[kk];
#pragma unroll
            for (int i = 0; i < 4; ++i) {
                float xs = ((const float*)&xv[i])[kk];
#pragma unroll
                for (int j = 0; j < 4; ++j) {
                    acc[i][j]     = fmaf(xs, wf0[j], acc[i][j]);
                    acc[i][j + 4] = fmaf(xs, wf1[j], acc[i][j + 4]);
                }
            }
        }
    }
#pragma unroll
    for (int i = 0; i < 4; ++i) {
        int r = r0 + i;
        if (r >= n) continue;
        float s = dinv[r];
        float4 o0, o1;
        o0.x = acc[i][0] * s; o0.y = acc[i][1] * s; o0.z = acc[i][2] * s; o0.w = acc[i][3] * s;
        o1.x = acc[i][4] * s; o1.y = acc[i][5] * s; o1.z = acc[i][6] * s; o1.w = acc[i][7] * s;
        float* hr = H2 + (size_t)r * 64 + c0;
        *(float4*)hr = o0;
        *(float4*)(hr + 4) = o1;
    }
}

// ---------- layer-1 gather (128-d), half-wave float4 ----------
// Row = 32 lanes x float4. half = lane>>5 processes edges j+half; 2 edges per
// load instruction, unroll 8 -> 4 dwordx4 in flight per lane.
__global__ __launch_bounds__(256) void k_gather128(const float* __restrict__ Hs,
                                                   const float* __restrict__ dinv,
                                                   const int* __restrict__ row_ptr,
                                                   const int* __restrict__ col,
                                                   float* __restrict__ out, int n) {
    int wave = threadIdx.x >> 6;
    int lane = threadIdx.x & 63;
    int half = lane >> 5, hl = lane & 31;
    int node = blockIdx.x * 4 + wave;
    if (node >= n) return;
    int beg = row_ptr[node], end = row_ptr[node + 1];
    int deg = end - beg;

    float4 acc = {0.f, 0.f, 0.f, 0.f};
    for (int base = 0; base < deg; base += 64) {
        int m = deg - base; if (m > 64) m = 64;
        int cl = (lane < m) ? col[beg + base + lane] : 0;
        int j = 0;
        for (; j + 8 <= m; j += 8) {
            int s0 = __shfl(cl, j + 0 + half);
            int s1 = __shfl(cl, j + 2 + half);
            int s2 = __shfl(cl, j + 4 + half);
            int s3 = __shfl(cl, j + 6 + half);
            float4 t0 = *(const float4*)(Hs + (size_t)s0 * 128 + hl * 4);
            float4 t1 = *(const float4*)(Hs + (size_t)s1 * 128 + hl * 4);
            float4 t2 = *(const float4*)(Hs + (size_t)s2 * 128 + hl * 4);
            float4 t3 = *(const float4*)(Hs + (size_t)s3 * 128 + hl * 4);
            acc.x += (t0.x + t1.x) + (t2.x + t3.x);
            acc.y += (t0.y + t1.y) + (t2.y + t3.y);
            acc.z += (t0.z + t1.z) + (t2.z + t3.z);
            acc.w += (t0.w + t1.w) + (t2.w + t3.w);
        }
        for (; j < m; j += 2) {
            int jj = j + half;
            bool ok = jj < m;
            int s = __shfl(cl, ok ? jj : j);
            float w = ok ? 1.f : 0.f;
            float4 t = *(const float4*)(Hs + (size_t)s * 128 + hl * 4);
            acc.x = fmaf(t.x, w, acc.x);
            acc.y = fmaf(t.y, w, acc.y);
            acc.z = fmaf(t.z, w, acc.z);
            acc.w = fmaf(t.w, w, acc.w);
        }
    }
    // combine the two half-wave partials
    acc.x += __shfl_xor(acc.x, 32);
    acc.y += __shfl_xor(acc.y, 32);
    acc.z += __shfl_xor(acc.z, 32);
    acc.w += __shfl_xor(acc.w, 32);
    if (half == 0) {
        float4 self = *(const float4*)(Hs + (size_t)node * 128 + hl * 4);
        float dd = dinv[node];
        float4 o;
        o.x = (acc.x + self.x) * dd;
        o.y = (acc.y + self.y) * dd;
        o.z = (acc.z + self.z) * dd;
        o.w = (acc.w + self.w) * dd;
        *(float4*)(out + (size_t)node * 128 + hl * 4) = o;
    }
}

// ---------- layer-2 gather (64-d) + FC, quarter-wave float4 ----------
// Row = 16 lanes x float4; q = lane>>4 processes edges j+q; 4 edges per load.
__global__ __launch_bounds__(256) void k_gather_fc(const float* __restrict__ Hs,
                                                   const float* __restrict__ dinv,
                                                   const int* __restrict__ row_ptr,
                                                   const int* __restrict__ col,
                                                   const float* __restrict__ b2,
                                                   const float* __restrict__ Wfc,
                                                   const float* __restrict__ bfc,
                                                   float* __restrict__ out, int n) {
    int wave = threadIdx.x >> 6;
    int lane = threadIdx.x & 63;
    int q = lane >> 4, ql = lane & 15;
    float wrow[10];
#pragma unroll
    for (int j = 0; j < 10; ++j) wrow[j] = Wfc[lane * 10 + j];
    float b2c = b2[lane];

    int node = blockIdx.x * 4 + wave;
    if (node >= n) return;
    int beg = row_ptr[node], end = row_ptr[node + 1];
    int deg = end - beg;

    float4 acc = {0.f, 0.f, 0.f, 0.f};
    for (int base = 0; base < deg; base += 64) {
        int m = deg - base; if (m > 64) m = 64;
        int cl = (lane < m) ? col[beg + base + lane] : 0;
        int j = 0;
        for (; j + 16 <= m; j += 16) {
            int s0 = __shfl(cl, j + 0 + q);
            int s1 = __shfl(cl, j + 4 + q);
            int s2 = __shfl(cl, j + 8 + q);
            int s3 = __shfl(cl, j + 12 + q);
            float4 t0 = *(const float4*)(Hs + (size_t)s0 * 64 + ql * 4);
            float4 t1 = *(const float4*)(Hs + (size_t)s1 * 64 + ql * 4);
            float4 t2 = *(const float4*)(Hs + (size_t)s2 * 64 + ql * 4);
            float4 t3 = *(const float4*)(Hs + (size_t)s3 * 64 + ql * 4);
            acc.x += (t0.x + t1.x) + (t2.x + t3.x);
            acc.y += (t0.y + t1.y) + (t2.y + t3.y);
            acc.z += (t0.z + t1.z) + (t2.z + t3.z);
            acc.w += (t0.w + t1.w) + (t2.w + t3.w);
        }
        for (; j < m; j += 4) {
            int jj = j + q;
            bool ok = jj < m;
            int s = __shfl(cl, ok ? jj : j);
            float w = ok ? 1.f : 0.f;
            float4 t = *(const float4*)(Hs + (size_t)s * 64 + ql * 4);
            acc.x = fmaf(t.x, w, acc.x);
            acc.y = fmaf(t.y, w, acc.y);
            acc.z = fmaf(t.z, w, acc.z);
            acc.w = fmaf(t.w, w, acc.w);
        }
    }
    // combine 4 quarter partials -> lanes hold col-set sums replicated
    acc.x += __shfl_xor(acc.x, 32);
    acc.y += __shfl_xor(acc.y, 32);
    acc.z += __shfl_xor(acc.z, 32);
    acc.w += __shfl_xor(acc.w, 32);
    acc.x += __shfl_xor(acc.x, 16);
    acc.y += __shfl_xor(acc.y, 16);
    acc.z += __shfl_xor(acc.z, 16);
    acc.w += __shfl_xor(acc.w, 16);
    // redistribute to 64-lane layout: lane L wants col L = component L&3 of lane L>>2
    int srcl = lane >> 2;
    float a0 = __shfl(acc.x, srcl);
    float a1 = __shfl(acc.y, srcl);
    float a2 = __shfl(acc.z, srcl);
    float a3 = __shfl(acc.w, srcl);
    int rr = lane & 3;
    float aggv = (rr == 0) ? a0 : (rr == 1) ? a1 : (rr == 2) ? a2 : a3;
    float selfv = Hs[(size_t)node * 64 + lane];
    float v = fmaxf((aggv + selfv) * dinv[node] + b2c, 0.f);
    float p[10];
#pragma unroll
    for (int j = 0; j < 10; ++j) p[j] = v * wrow[j];
#pragma unroll
    for (int off = 32; off > 0; off >>= 1)
#pragma unroll
        for (int j = 0; j < 10; ++j) p[j] += __shfl_xor(p[j], off);
    if (lane == 0) {
        float* o = out + (size_t)node * 10;
#pragma unroll
        for (int j = 0; j < 10; ++j) o[j] = p[j] + bfc[j];
    }
}

static inline int cdiv(long long a, int b) { return (int)((a + b - 1) / b); }

extern "C" void kernel_launch(void* const* d_in, const int* in_sizes, int n_in,
                              void* d_out, int out_size, void* d_ws, size_t ws_size,
                              hipStream_t stream) {
    const float* x   = (const float*)d_in[0];
    const int*   ei  = (const int*)d_in[1];
    const float* W1  = (const float*)d_in[2];
    const float* b1  = (const float*)d_in[3];
    const float* W2  = (const float*)d_in[4];
    const float* b2  = (const float*)d_in[5];
    const float* Wfc = (const float*)d_in[6];
    const float* bfc = (const float*)d_in[7];
    float* out = (float*)d_out;

    const int N = in_sizes[0] / 128;   // 100000
    const int E = in_sizes[1] / 2;     // 1600000
    const int* src = ei;
    const int* dst = ei + E;
    const int nb = cdiv(N, 256);       // 391

    char* ws = (char*)d_ws;
    size_t off = 0;
    auto alloc = [&](size_t bytes) { void* p = ws + off; off = (off + bytes + 255) & ~(size_t)255; return p; };
    float* dinv    = (float*)alloc((size_t)N * 4);
    int*   deg     = (int*)  alloc((size_t)N * 4);
    int*   row_ptr = (int*)  alloc((size_t)(N + 1) * 4);
    int*   cursor  = (int*)  alloc((size_t)N * 4);
    int*   bsum    = (int*)  alloc(512 * 4);
    int*   boff    = (int*)  alloc(512 * 4);
    int*   col     = (int*)  alloc((size_t)E * 4);
    float* bufA    = (float*)alloc((size_t)N * 128 * 4);
    float* bufB    = (float*)alloc((size_t)N * 128 * 4);

    // CSR build
    hipMemsetAsync(deg, 0, (size_t)N * 4, stream);
    k_deg_count<<<cdiv(E, TPB), TPB, 0, stream>>>(dst, deg, E);
    k_scan_partial<<<nb, 256, 0, stream>>>(deg, bsum, N);
    k_scan_bsums<<<1, 512, 0, stream>>>(bsum, boff, nb);
    k_scan_final<<<nb, 256, 0, stream>>>(deg, boff, row_ptr, cursor, dinv, N);

    // interleaved fill | GEMM1: grid = 5*ceil(gemmBlocks/3); 2/5 fill, 3/5 gemm
    const int gemmBlocks = cdiv(N, 64);              // 1563
    const int groups = cdiv(gemmBlocks, 3);          // 521
    const int nFill = groups * 2;                    // 1042
    k_fill_gemm1<<<groups * 5, 256, 0, stream>>>(
        src, dst, cursor, col, E, x, W1, dinv, bufA, N, nFill);

    // layer 1 aggregate
    k_gather128<<<cdiv(N, 4), 256, 0, stream>>>(bufA, dinv, row_ptr, col, bufB, N);

    // layer 2 transform then aggregate+FC (writes d_out directly)
    k_gemm2<<<cdiv(N, 128), 256, 0, stream>>>(bufB, W2, b1, dinv, bufA, N);
    k_gather_fc<<<cdiv(N, 4), 256, 0, stream>>>(bufA, dinv, row_ptr, col,
                                                b2, Wfc, bfc, out, N);
}

// Round 6
// 537.073 us; speedup vs baseline: 1.2111x; 1.1302x over previous
//
#include <hip/hip_runtime.h>
#include <hip/hip_fp16.h>

// GCN 2-layer + FC. Round 6: fp16 intermediates (H1', agg1, H2') halve gather
// traffic; quarter-wave (128-d) / eighth-wave (64-d) half8 gathers; CSR fill
// with 8 batched atomics per thread; {fill|GEMM1} interleaved grid.

static constexpr int TPB = 256;

union HV8 { uint4 u; __half2 h2[4]; __half h[8]; };

__device__ inline void acc8(float* a, const HV8& v, float w) {
#pragma unroll
    for (int i = 0; i < 4; ++i) {
        float2 f = __half22float2(v.h2[i]);
        a[2 * i]     = fmaf(f.x, w, a[2 * i]);
        a[2 * i + 1] = fmaf(f.y, w, a[2 * i + 1]);
    }
}

// ---------- CSR build ----------
__global__ __launch_bounds__(256) void k_deg_count(const int* __restrict__ dst,
                                                   int* __restrict__ deg, int E) {
    int e = blockIdx.x * blockDim.x + threadIdx.x;
    if (e < E) atomicAdd(&deg[dst[e]], 1);
}

__global__ __launch_bounds__(256) void k_scan_partial(const int* __restrict__ deg,
                                                      int* __restrict__ bsum, int n) {
    __shared__ int lds[256];
    int i = blockIdx.x * 256 + threadIdx.x;
    lds[threadIdx.x] = (i < n) ? deg[i] : 0;
    __syncthreads();
    for (int off = 128; off > 0; off >>= 1) {
        if (threadIdx.x < off) lds[threadIdx.x] += lds[threadIdx.x + off];
        __syncthreads();
    }
    if (threadIdx.x == 0) bsum[blockIdx.x] = lds[0];
}

__global__ __launch_bounds__(512) void k_scan_bsums(const int* __restrict__ bsum,
                                                    int* __restrict__ boff, int nb) {
    __shared__ int lds[512];
    int t = threadIdx.x;
    int v = (t < nb) ? bsum[t] : 0;
    lds[t] = v;
    __syncthreads();
    for (int off = 1; off < 512; off <<= 1) {
        int add = (t >= off) ? lds[t - off] : 0;
        __syncthreads();
        lds[t] += add;
        __syncthreads();
    }
    if (t < nb) boff[t] = lds[t] - v;
}

__global__ __launch_bounds__(256) void k_scan_final(const int* __restrict__ deg,
                                                    const int* __restrict__ boff,
                                                    int* __restrict__ row_ptr,
                                                    int* __restrict__ cursor,
                                                    float* __restrict__ dinv, int n) {
    __shared__ int lds[256];
    int i = blockIdx.x * 256 + threadIdx.x;
    int v = (i < n) ? deg[i] : 0;
    lds[threadIdx.x] = v;
    __syncthreads();
    for (int off = 1; off < 256; off <<= 1) {
        int add = (threadIdx.x >= off) ? lds[threadIdx.x - off] : 0;
        __syncthreads();
        lds[threadIdx.x] += add;
        __syncthreads();
    }
    if (i < n) {
        int incl = lds[threadIdx.x];
        int rp = boff[blockIdx.x] + (incl - v);
        row_ptr[i] = rp;
        cursor[i]  = rp;
        dinv[i]    = rsqrtf((float)(v + 1));
        if (i == n - 1) row_ptr[n] = rp + v;
    }
}

// ---------- interleaved {fill | gemm1} ----------
// blockIdx%5<2 -> fill role (2048 edges/block: 8 batched atomics per thread);
// else -> GEMM1 role: Hh = fp16((X@W1)*dinv), 4x8 micro-tile.
__global__ __launch_bounds__(256) void k_fill_gemm1(
        const int* __restrict__ src, const int* __restrict__ dst,
        int* __restrict__ cursor, int* __restrict__ col, int E,
        const float* __restrict__ X, const float* __restrict__ W,
        const float* __restrict__ dinv, __half* __restrict__ Hh, int n,
        int nFill) {
    int qg = blockIdx.x / 5, r5 = blockIdx.x % 5;
    if (r5 < 2) {
        int fid = qg * 2 + r5;
        const long long CHUNK = 256 * 8;
        for (long long w = (long long)fid * CHUNK; w < E; w += (long long)nFill * CHUNK) {
            int d[8], s[8], p[8];
#pragma unroll
            for (int i = 0; i < 8; ++i) {
                long long e = w + i * 256 + threadIdx.x;
                bool ok = e < E;
                d[i] = ok ? dst[e] : 0;
                s[i] = ok ? src[e] : 0;
            }
#pragma unroll
            for (int i = 0; i < 8; ++i) {
                long long e = w + i * 256 + threadIdx.x;
                p[i] = (e < E) ? atomicAdd(&cursor[d[i]], 1) : 0;
            }
#pragma unroll
            for (int i = 0; i < 8; ++i) {
                long long e = w + i * 256 + threadIdx.x;
                if (e < E) col[p[i]] = s[i];
            }
        }
        return;
    }
    int bid = qg * 3 + (r5 - 2);
    int t = threadIdx.x;
    int tc = t & 15, tr = t >> 4;
    int c0 = tc * 8;
    int r0 = bid * 64 + tr * 4;

    const float* xp[4];
#pragma unroll
    for (int i = 0; i < 4; ++i) {
        int rr = r0 + i;
        xp[i] = X + (size_t)(rr < n ? rr : 0) * 128;
    }
    float acc[4][8];
#pragma unroll
    for (int i = 0; i < 4; ++i)
#pragma unroll
        for (int j = 0; j < 8; ++j) acc[i][j] = 0.f;

    for (int k0 = 0; k0 < 128; k0 += 4) {
        float4 xv[4];
#pragma unroll
        for (int i = 0; i < 4; ++i) xv[i] = *(const float4*)(xp[i] + k0);
        float4 w0[4], w1[4];
#pragma unroll
        for (int kk = 0; kk < 4; ++kk) {
            const float* wr = W + (size_t)(k0 + kk) * 128 + c0;
            w0[kk] = *(const float4*)wr;
            w1[kk] = *(const float4*)(wr + 4);
        }
#pragma unroll
        for (int kk = 0; kk < 4; ++kk) {
            const float* wf0 = (const float*)&w0[kk];
            const float* wf1 = (const float*)&w1[kk];
#pragma unroll
            for (int i = 0; i < 4; ++i) {
                float xs = ((const float*)&xv[i])[kk];
#pragma unroll
                for (int j = 0; j < 4; ++j) {
                    acc[i][j]     = fmaf(xs, wf0[j], acc[i][j]);
                    acc[i][j + 4] = fmaf(xs, wf1[j], acc[i][j + 4]);
                }
            }
        }
    }
#pragma unroll
    for (int i = 0; i < 4; ++i) {
        int rr = r0 + i;
        if (rr >= n) continue;
        float s = dinv[rr];
        HV8 o;
#pragma unroll
        for (int j = 0; j < 8; ++j) o.h[j] = __float2half(acc[i][j] * s);
        *(uint4*)(Hh + (size_t)rr * 128 + c0) = o.u;
    }
}

// ---------- layer-1 gather (128-d fp16), quarter-wave half8 ----------
// Row = 16 lanes x 8 halfs; qi = lane>>4 handles edge slot; 4 edges per load
// instruction, unroll 4 -> 16 edges per j-step.
__global__ __launch_bounds__(256) void k_gather128(const __half* __restrict__ Hs,
                                                   const float* __restrict__ dinv,
                                                   const int* __restrict__ row_ptr,
                                                   const int* __restrict__ col,
                                                   __half* __restrict__ outh, int n) {
    int wave = threadIdx.x >> 6;
    int lane = threadIdx.x & 63;
    int qi = lane >> 4, ql = lane & 15;
    int node = blockIdx.x * 4 + wave;
    if (node >= n) return;
    int beg = row_ptr[node], end = row_ptr[node + 1];
    int deg = end - beg;

    float acc[8];
#pragma unroll
    for (int v = 0; v < 8; ++v) acc[v] = 0.f;

    for (int base = 0; base < deg; base += 64) {
        int m = deg - base; if (m > 64) m = 64;
        int cl = (lane < m) ? col[beg + base + lane] : 0;
        int j = 0;
        for (; j + 16 <= m; j += 16) {
            int s0 = __shfl(cl, j + 0  + qi);
            int s1 = __shfl(cl, j + 4  + qi);
            int s2 = __shfl(cl, j + 8  + qi);
            int s3 = __shfl(cl, j + 12 + qi);
            HV8 u0, u1, u2, u3;
            u0.u = *(const uint4*)(Hs + (size_t)s0 * 128 + ql * 8);
            u1.u = *(const uint4*)(Hs + (size_t)s1 * 128 + ql * 8);
            u2.u = *(const uint4*)(Hs + (size_t)s2 * 128 + ql * 8);
            u3.u = *(const uint4*)(Hs + (size_t)s3 * 128 + ql * 8);
            acc8(acc, u0, 1.f); acc8(acc, u1, 1.f);
            acc8(acc, u2, 1.f); acc8(acc, u3, 1.f);
        }
        for (; j < m; j += 4) {
            int jj = j + qi;
            bool ok = jj < m;
            int s = __shfl(cl, ok ? jj : j);
            HV8 u; u.u = *(const uint4*)(Hs + (size_t)s * 128 + ql * 8);
            acc8(acc, u, ok ? 1.f : 0.f);
        }
    }
    // combine 4 quarter partials
#pragma unroll
    for (int v = 0; v < 8; ++v) {
        acc[v] += __shfl_xor(acc[v], 32);
        acc[v] += __shfl_xor(acc[v], 16);
    }
    if (qi == 0) {
        HV8 su; su.u = *(const uint4*)(Hs + (size_t)node * 128 + ql * 8);
        float dd = dinv[node];
        HV8 o;
#pragma unroll
        for (int i = 0; i < 4; ++i) {
            float2 f = __half22float2(su.h2[i]);
            o.h[2 * i]     = __float2half((acc[2 * i]     + f.x) * dd);
            o.h[2 * i + 1] = __float2half((acc[2 * i + 1] + f.y) * dd);
        }
        *(uint4*)(outh + (size_t)node * 128 + ql * 8) = o.u;
    }
}

// ---------- GEMM2: Hh2 = fp16((relu(f32(A)+b1) @ W2) * dinv); A fp16 ----------
__global__ __launch_bounds__(256) void k_gemm2(const __half* __restrict__ A,
                                               const float* __restrict__ W2,
                                               const float* __restrict__ b1,
                                               const float* __restrict__ dinv,
                                               __half* __restrict__ Hh2, int n) {
    int t = threadIdx.x;
    int tc = t & 7, tr = t >> 3;
    int c0 = tc * 8;
    int r0 = blockIdx.x * 128 + tr * 4;

    const __half* xp[4];
#pragma unroll
    for (int i = 0; i < 4; ++i) {
        int r = r0 + i;
        xp[i] = A + (size_t)(r < n ? r : 0) * 128;
    }
    float acc[4][8];
#pragma unroll
    for (int i = 0; i < 4; ++i)
#pragma unroll
        for (int j = 0; j < 8; ++j) acc[i][j] = 0.f;

    for (int k0 = 0; k0 < 128; k0 += 8) {
        float4 bbl = *(const float4*)(b1 + k0);
        float4 bbh = *(const float4*)(b1 + k0 + 4);
        const float* bb = (const float*)&bbl;   // bbl/bbh contiguous on stack? use explicit
        float xf[4][8];
#pragma unroll
        for (int i = 0; i < 4; ++i) {
            HV8 u; u.u = *(const uint4*)(xp[i] + k0);
#pragma unroll
            for (int p = 0; p < 4; ++p) {
                float2 f = __half22float2(u.h2[p]);
                float b0 = (p < 2) ? ((const float*)&bbl)[2 * p]     : ((const float*)&bbh)[2 * p - 4];
                float b1v = (p < 2) ? ((const float*)&bbl)[2 * p + 1] : ((const float*)&bbh)[2 * p - 3];
                xf[i][2 * p]     = fmaxf(f.x + b0, 0.f);
                xf[i][2 * p + 1] = fmaxf(f.y + b1v, 0.f);
            }
        }
        (void)bb;
#pragma unroll
        for (int kk = 0; kk < 8; ++kk) {
            const float* wr = W2 + (size_t)(k0 + kk) * 64 + c0;
            float4 w0 = *(const float4*)wr;
            float4 w1 = *(const float4*)(wr + 4);
            const float* wf0 = (const float*)&w0;
            const float* wf1 = (const float*)&w1;
#pragma unroll
            for (int i = 0; i < 4; ++i) {
                float xs = xf[i][kk];
#pragma unroll
                for (int j = 0; j < 4; ++j) {
                    acc[i][j]     = fmaf(xs, wf0[j], acc[i][j]);
                    acc[i][j + 4] = fmaf(xs, wf1[j], acc[i][j + 4]);
                }
            }
        }
    }
#pragma unroll
    for (int i = 0; i < 4; ++i) {
        int r = r0 + i;
        if (r >= n) continue;
        float s = dinv[r];
        HV8 o;
#pragma unroll
        for (int j = 0; j < 8; ++j) o.h[j] = __float2half(acc[i][j] * s);
        *(uint4*)(Hh2 + (size_t)r * 64 + c0) = o.u;
    }
}

// ---------- layer-2 gather (64-d fp16) + FC, eighth-wave half8 ----------
__global__ __launch_bounds__(256) void k_gather_fc(const __half* __restrict__ Hs,
                                                   const float* __restrict__ dinv,
                                                   const int* __restrict__ row_ptr,
                                                   const int* __restrict__ col,
                                                   const float* __restrict__ b2,
                                                   const float* __restrict__ Wfc,
                                                   const float* __restrict__ bfc,
                                                   float* __restrict__ out, int n) {
    int wave = threadIdx.x >> 6;
    int lane = threadIdx.x & 63;
    int oi = lane >> 3, ol = lane & 7;
    float wrow[10];
#pragma unroll
    for (int j = 0; j < 10; ++j) wrow[j] = Wfc[lane * 10 + j];
    float b2c = b2[lane];

    int node = blockIdx.x * 4 + wave;
    if (node >= n) return;
    int beg = row_ptr[node], end = row_ptr[node + 1];
    int deg = end - beg;

    float acc[8];
#pragma unroll
    for (int v = 0; v < 8; ++v) acc[v] = 0.f;

    for (int base = 0; base < deg; base += 64) {
        int m = deg - base; if (m > 64) m = 64;
        int cl = (lane < m) ? col[beg + base + lane] : 0;
        int j = 0;
        for (; j + 16 <= m; j += 16) {
            int s0 = __shfl(cl, j + oi);
            int s1 = __shfl(cl, j + 8 + oi);
            HV8 u0, u1;
            u0.u = *(const uint4*)(Hs + (size_t)s0 * 64 + ol * 8);
            u1.u = *(const uint4*)(Hs + (size_t)s1 * 64 + ol * 8);
            acc8(acc, u0, 1.f); acc8(acc, u1, 1.f);
        }
        for (; j < m; j += 8) {
            int jj = j + oi;
            bool ok = jj < m;
            int s = __shfl(cl, ok ? jj : j);
            HV8 u; u.u = *(const uint4*)(Hs + (size_t)s * 64 + ol * 8);
            acc8(acc, u, ok ? 1.f : 0.f);
        }
    }
    // combine 8 partials: reduce across oi bits (3,4,5)
#pragma unroll
    for (int v = 0; v < 8; ++v) {
        acc[v] += __shfl_xor(acc[v], 32);
        acc[v] += __shfl_xor(acc[v], 16);
        acc[v] += __shfl_xor(acc[v], 8);
    }
    // redistribute: lane L wants col L = elem (L&7) of group (L>>3); group g's
    // sums live in any lane with ol==g, e.g. lane g.
    int srcl = lane >> 3;
    float vals[8];
#pragma unroll
    for (int v = 0; v < 8; ++v) vals[v] = __shfl(acc[v], srcl);
    int e = lane & 7;
    float aggv = vals[0];
#pragma unroll
    for (int v = 1; v < 8; ++v) aggv = (e == v) ? vals[v] : aggv;

    float selfv = __half2float(Hs[(size_t)node * 64 + lane]);
    float v = fmaxf((aggv + selfv) * dinv[node] + b2c, 0.f);
    float p[10];
#pragma unroll
    for (int j = 0; j < 10; ++j) p[j] = v * wrow[j];
#pragma unroll
    for (int off = 32; off > 0; off >>= 1)
#pragma unroll
        for (int j = 0; j < 10; ++j) p[j] += __shfl_xor(p[j], off);
    if (lane == 0) {
        float* o = out + (size_t)node * 10;
#pragma unroll
        for (int j = 0; j < 10; ++j) o[j] = p[j] + bfc[j];
    }
}

static inline int cdiv(long long a, int b) { return (int)((a + b - 1) / b); }

extern "C" void kernel_launch(void* const* d_in, const int* in_sizes, int n_in,
                              void* d_out, int out_size, void* d_ws, size_t ws_size,
                              hipStream_t stream) {
    const float* x   = (const float*)d_in[0];
    const int*   ei  = (const int*)d_in[1];
    const float* W1  = (const float*)d_in[2];
    const float* b1  = (const float*)d_in[3];
    const float* W2  = (const float*)d_in[4];
    const float* b2  = (const float*)d_in[5];
    const float* Wfc = (const float*)d_in[6];
    const float* bfc = (const float*)d_in[7];
    float* out = (float*)d_out;

    const int N = in_sizes[0] / 128;   // 100000
    const int E = in_sizes[1] / 2;     // 1600000
    const int* src = ei;
    const int* dst = ei + E;
    const int nb = cdiv(N, 256);       // 391

    char* ws = (char*)d_ws;
    size_t off = 0;
    auto alloc = [&](size_t bytes) { void* p = ws + off; off = (off + bytes + 255) & ~(size_t)255; return p; };
    float*  dinv    = (float*) alloc((size_t)N * 4);
    int*    deg     = (int*)   alloc((size_t)N * 4);
    int*    row_ptr = (int*)   alloc((size_t)(N + 1) * 4);
    int*    cursor  = (int*)   alloc((size_t)N * 4);
    int*    bsum    = (int*)   alloc(512 * 4);
    int*    boff    = (int*)   alloc(512 * 4);
    int*    col     = (int*)   alloc((size_t)E * 4);
    __half* Hh1     = (__half*)alloc((size_t)N * 128 * 2);  // gemm1 out (pre-scaled)
    __half* Ah1     = (__half*)alloc((size_t)N * 128 * 2);  // gather128 out
    __half* Hh2     = (__half*)alloc((size_t)N * 64 * 2);   // gemm2 out (pre-scaled)

    // CSR build
    hipMemsetAsync(deg, 0, (size_t)N * 4, stream);
    k_deg_count<<<cdiv(E, TPB), TPB, 0, stream>>>(dst, deg, E);
    k_scan_partial<<<nb, 256, 0, stream>>>(deg, bsum, N);
    k_scan_bsums<<<1, 512, 0, stream>>>(bsum, boff, nb);
    k_scan_final<<<nb, 256, 0, stream>>>(deg, boff, row_ptr, cursor, dinv, N);

    // interleaved fill | GEMM1
    const int gemmBlocks = cdiv(N, 64);              // 1563
    const int groups = cdiv(gemmBlocks, 3);          // 521
    const int nFill = groups * 2;                    // 1042
    k_fill_gemm1<<<groups * 5, 256, 0, stream>>>(
        src, dst, cursor, col, E, x, W1, dinv, Hh1, N, nFill);

    // layer 1 aggregate (fp16 in/out)
    k_gather128<<<cdiv(N, 4), 256, 0, stream>>>(Hh1, dinv, row_ptr, col, Ah1, N);

    // layer 2 transform then aggregate+FC (writes d_out directly)
    k_gemm2<<<cdiv(N, 128), 256, 0, stream>>>(Ah1, W2, b1, dinv, Hh2, N);
    k_gather_fc<<<cdiv(N, 4), 256, 0, stream>>>(Hh2, dinv, row_ptr, col,
                                                b2, Wfc, bfc, out, N);
}

// Round 7
// 490.183 us; speedup vs baseline: 1.3270x; 1.0957x over previous
//
#include <hip/hip_runtime.h>
#include <hip/hip_fp16.h>

// GCN 2-layer + FC. Round 7: locality-aware CSR build.
//  B1: bucket-scatter edges (196 buckets x 512 nodes) with LDS write-combining
//      (16-entry/bucket staging, full-line flushes) -> ~1x write amplification.
//  B2 (interleaved 1:8 with GEMM1): per-bucket LDS histogram (replaces
//      deg_count + global scans) + counting sort into a 32KB L2-resident col
//      region. GEMM1 writes unscaled fp16 H1; gather128 applies dinv[src] as
//      the per-edge fmaf weight.

static constexpr int NB   = 196;   // buckets = ceil(100000/512)
static constexpr int NPB  = 512;   // nodes per bucket
static constexpr int BCAP = 9216;  // per-bucket edge capacity (mean 8192 + 11 sigma)
static constexpr int STG  = 16;    // staged entries per bucket = one 64B line

union HV8 { uint4 u; __half2 h2[4]; __half h[8]; };

__device__ inline void acc8(float* a, const HV8& v, float w) {
#pragma unroll
    for (int i = 0; i < 4; ++i) {
        float2 f = __half22float2(v.h2[i]);
        a[2 * i]     = fmaf(f.x, w, a[2 * i]);
        a[2 * i + 1] = fmaf(f.y, w, a[2 * i + 1]);
    }
}

// ---------- B1: bucket scatter with LDS write-combining ----------
__global__ __launch_bounds__(256) void k_bucket_scatter(
        const int* __restrict__ src, const int* __restrict__ dst, int E,
        int* __restrict__ gcursor,          // [NB], zero-initialized
        unsigned* __restrict__ ebuf) {      // [NB*BCAP]
    __shared__ alignas(16) unsigned stg[NB][STG];
    __shared__ int cnt[NB];
    __shared__ int anyWant;
    int tid = threadIdx.x;
    for (int i = tid; i < NB; i += 256) cnt[i] = 0;
    __syncthreads();

    long long stride = (long long)gridDim.x * 256;
    long long e = (long long)blockIdx.x * 256 + tid;
    unsigned carry = 0; int carryB = 0; bool hasCarry = false;

    while (true) {
        if (tid == 0) anyWant = 0;
        __syncthreads();
        bool want = false; unsigned pk = 0; int b = 0;
        if (hasCarry) {
            pk = carry; b = carryB; hasCarry = false; want = true;
        } else if (e < E) {
            int d = dst[e];
            int s = src[e];
            b  = d >> 9;
            pk = ((unsigned)(d & 511) << 17) | (unsigned)s;
            e += stride;
            want = true;
        }
        if (want) {
            anyWant = 1;
            int pos = atomicAdd(&cnt[b], 1);
            if (pos < STG) {
                stg[b][pos] = pk;
            } else {
                carry = pk; carryB = b; hasCarry = true;   // retry next round
            }
        }
        __syncthreads();
        if (!anyWant) break;
        // flush full buckets (one thread per bucket, one 64B line per flush)
        if (tid < NB) {
            if (cnt[tid] >= STG) {
                int rel = atomicAdd(&gcursor[tid], STG);
                if (rel + STG <= BCAP) {
                    uint4* dp = (uint4*)(ebuf + (size_t)tid * BCAP + rel);
                    const uint4* sp = (const uint4*)&stg[tid][0];
                    dp[0] = sp[0]; dp[1] = sp[1]; dp[2] = sp[2]; dp[3] = sp[3];
                }
                cnt[tid] = 0;
            }
        }
        __syncthreads();
    }
    // drain partial staging
    if (tid < NB) {
        int c = cnt[tid];
        if (c > 0) {
            if (c > STG) c = STG;
            int rel = atomicAdd(&gcursor[tid], c);
            if (rel + c <= BCAP) {
                unsigned* dp = ebuf + (size_t)tid * BCAP + rel;
                for (int i = 0; i < c; ++i) dp[i] = stg[tid][i];
            }
        }
    }
}

// ---------- bucket base exclusive scan (1 block) ----------
__global__ __launch_bounds__(256) void k_bucket_scan(const int* __restrict__ gcursor,
                                                     int* __restrict__ bucketBase) {
    __shared__ int lds[256];
    int t = threadIdx.x;
    int v = (t < NB) ? min(gcursor[t], BCAP) : 0;
    lds[t] = v;
    __syncthreads();
    for (int off = 1; off < 256; off <<= 1) {
        int add = (t >= off) ? lds[t - off] : 0;
        __syncthreads();
        lds[t] += add;
        __syncthreads();
    }
    if (t < NB) bucketBase[t] = lds[t] - v;
}

// ---------- fused: per-bucket CSR build (1/9 of blocks) | GEMM1 (8/9) ----------
__global__ __launch_bounds__(256) void k_csr_gemm1(
        const unsigned* __restrict__ ebuf, const int* __restrict__ gcursor,
        const int* __restrict__ bucketBase,
        int* __restrict__ row_ptr, int* __restrict__ col, float* __restrict__ dinv,
        int N_,
        const float* __restrict__ X, const float* __restrict__ W,
        __half* __restrict__ Hh, int gemmN) {
    int q = blockIdx.x / 9, r = blockIdx.x % 9;
    if (r == 8) {                       // grid == NB*9 -> q < NB always here
        __shared__ int hist[NPB];
        __shared__ int scanv[256];
        __shared__ int rp[NPB];
        int tid = threadIdx.x;
        int b = q;
        for (int i = tid; i < NPB; i += 256) hist[i] = 0;
        __syncthreads();
        int cntb = min(gcursor[b], BCAP);
        const unsigned* seg = ebuf + (size_t)b * BCAP;
        for (int i = tid; i < cntb; i += 256)
            atomicAdd(&hist[seg[i] >> 17], 1);
        __syncthreads();
        // exclusive scan of hist[512]: 2 elems/thread
        int a0 = hist[2 * tid], a1 = hist[2 * tid + 1];
        int s = a0 + a1;
        scanv[tid] = s;
        __syncthreads();
        for (int off = 1; off < 256; off <<= 1) {
            int add = (tid >= off) ? scanv[tid - off] : 0;
            __syncthreads();
            scanv[tid] += add;
            __syncthreads();
        }
        int excl = scanv[tid] - s;
        rp[2 * tid] = excl;
        rp[2 * tid + 1] = excl + a0;
        __syncthreads();
        int base = bucketBase[b];
        int node0 = b * NPB;
        for (int i = tid; i < NPB; i += 256) {
            int node = node0 + i;
            if (node < N_) {
                row_ptr[node] = base + rp[i];
                dinv[node] = rsqrtf((float)(hist[i] + 1));
            }
        }
        if (tid == 0 && b == NB - 1) row_ptr[N_] = base + cntb;
        __syncthreads();
        for (int i = tid; i < NPB; i += 256) rp[i] += base;   // rp -> global cursor
        __syncthreads();
        for (int i = tid; i < cntb; i += 256) {
            unsigned pk = seg[i];
            int pos = atomicAdd(&rp[pk >> 17], 1);
            col[pos] = (int)(pk & 0x1FFFFu);
        }
        return;
    }
    // ---- GEMM1 role: Hh = fp16(X @ W), unscaled ----
    int bid = q * 8 + r;
    int t = threadIdx.x;
    int tc = t & 15, tr = t >> 4;
    int c0 = tc * 8;
    int r0 = bid * 64 + tr * 4;
    if (r0 >= gemmN + 4 && r0 >= gemmN) { }   // rows guarded below

    const float* xp[4];
#pragma unroll
    for (int i = 0; i < 4; ++i) {
        int rr = r0 + i;
        xp[i] = X + (size_t)(rr < gemmN ? rr : 0) * 128;
    }
    float acc[4][8];
#pragma unroll
    for (int i = 0; i < 4; ++i)
#pragma unroll
        for (int j = 0; j < 8; ++j) acc[i][j] = 0.f;

    for (int k0 = 0; k0 < 128; k0 += 4) {
        float4 xv[4];
#pragma unroll
        for (int i = 0; i < 4; ++i) xv[i] = *(const float4*)(xp[i] + k0);
        float4 w0[4], w1[4];
#pragma unroll
        for (int kk = 0; kk < 4; ++kk) {
            const float* wr = W + (size_t)(k0 + kk) * 128 + c0;
            w0[kk] = *(const float4*)wr;
            w1[kk] = *(const float4*)(wr + 4);
        }
#pragma unroll
        for (int kk = 0; kk < 4; ++kk) {
            const float* wf0 = (const float*)&w0[kk];
            const float* wf1 = (const float*)&w1[kk];
#pragma unroll
            for (int i = 0; i < 4; ++i) {
                float xs = ((const float*)&xv[i])[kk];
#pragma unroll
                for (int j = 0; j < 4; ++j) {
                    acc[i][j]     = fmaf(xs, wf0[j], acc[i][j]);
                    acc[i][j + 4] = fmaf(xs, wf1[j], acc[i][j + 4]);
                }
            }
        }
    }
#pragma unroll
    for (int i = 0; i < 4; ++i) {
        int rr = r0 + i;
        if (rr >= gemmN) continue;
        HV8 o;
#pragma unroll
        for (int j = 0; j < 8; ++j) o.h[j] = __float2half(acc[i][j]);
        *(uint4*)(Hh + (size_t)rr * 128 + c0) = o.u;
    }
}

// ---------- layer-1 gather (128-d fp16), quarter-wave half8, dinv[src] weight ----------
__global__ __launch_bounds__(256) void k_gather128(const __half* __restrict__ Hs,
                                                   const float* __restrict__ dinv,
                                                   const int* __restrict__ row_ptr,
                                                   const int* __restrict__ col,
                                                   __half* __restrict__ outh, int n) {
    int wave = threadIdx.x >> 6;
    int lane = threadIdx.x & 63;
    int qi = lane >> 4, ql = lane & 15;
    int node = blockIdx.x * 4 + wave;
    if (node >= n) return;
    int beg = row_ptr[node], end = row_ptr[node + 1];
    int deg = end - beg;

    float acc[8];
#pragma unroll
    for (int v = 0; v < 8; ++v) acc[v] = 0.f;

    for (int base = 0; base < deg; base += 64) {
        int m = deg - base; if (m > 64) m = 64;
        int cl = (lane < m) ? col[beg + base + lane] : 0;
        int j = 0;
        for (; j + 16 <= m; j += 16) {
            int s0 = __shfl(cl, j + 0  + qi);
            int s1 = __shfl(cl, j + 4  + qi);
            int s2 = __shfl(cl, j + 8  + qi);
            int s3 = __shfl(cl, j + 12 + qi);
            float w0 = dinv[s0], w1 = dinv[s1], w2 = dinv[s2], w3 = dinv[s3];
            HV8 u0, u1, u2, u3;
            u0.u = *(const uint4*)(Hs + (size_t)s0 * 128 + ql * 8);
            u1.u = *(const uint4*)(Hs + (size_t)s1 * 128 + ql * 8);
            u2.u = *(const uint4*)(Hs + (size_t)s2 * 128 + ql * 8);
            u3.u = *(const uint4*)(Hs + (size_t)s3 * 128 + ql * 8);
            acc8(acc, u0, w0); acc8(acc, u1, w1);
            acc8(acc, u2, w2); acc8(acc, u3, w3);
        }
        for (; j < m; j += 4) {
            int jj = j + qi;
            bool ok = jj < m;
            int s = __shfl(cl, ok ? jj : j);
            float w = ok ? dinv[s] : 0.f;
            HV8 u; u.u = *(const uint4*)(Hs + (size_t)s * 128 + ql * 8);
            acc8(acc, u, w);
        }
    }
#pragma unroll
    for (int v = 0; v < 8; ++v) {
        acc[v] += __shfl_xor(acc[v], 32);
        acc[v] += __shfl_xor(acc[v], 16);
    }
    if (qi == 0) {
        HV8 su; su.u = *(const uint4*)(Hs + (size_t)node * 128 + ql * 8);
        float dn = dinv[node];
        HV8 o;
#pragma unroll
        for (int i = 0; i < 4; ++i) {
            float2 f = __half22float2(su.h2[i]);
            o.h[2 * i]     = __float2half((acc[2 * i]     + dn * f.x) * dn);
            o.h[2 * i + 1] = __float2half((acc[2 * i + 1] + dn * f.y) * dn);
        }
        *(uint4*)(outh + (size_t)node * 128 + ql * 8) = o.u;
    }
}

// ---------- GEMM2: Hh2 = fp16((relu(f32(A)+b1) @ W2) * dinv); A fp16 ----------
__global__ __launch_bounds__(256) void k_gemm2(const __half* __restrict__ A,
                                               const float* __restrict__ W2,
                                               const float* __restrict__ b1,
                                               const float* __restrict__ dinv,
                                               __half* __restrict__ Hh2, int n) {
    int t = threadIdx.x;
    int tc = t & 7, tr = t >> 3;
    int c0 = tc * 8;
    int r0 = blockIdx.x * 128 + tr * 4;

    const __half* xp[4];
#pragma unroll
    for (int i = 0; i < 4; ++i) {
        int r = r0 + i;
        xp[i] = A + (size_t)(r < n ? r : 0) * 128;
    }
    float acc[4][8];
#pragma unroll
    for (int i = 0; i < 4; ++i)
#pragma unroll
        for (int j = 0; j < 8; ++j) acc[i][j] = 0.f;

    for (int k0 = 0; k0 < 128; k0 += 8) {
        float bb[8];
#pragma unroll
        for (int p = 0; p < 8; ++p) bb[p] = b1[k0 + p];
        float xf[4][8];
#pragma unroll
        for (int i = 0; i < 4; ++i) {
            HV8 u; u.u = *(const uint4*)(xp[i] + k0);
#pragma unroll
            for (int p = 0; p < 4; ++p) {
                float2 f = __half22float2(u.h2[p]);
                xf[i][2 * p]     = fmaxf(f.x + bb[2 * p], 0.f);
                xf[i][2 * p + 1] = fmaxf(f.y + bb[2 * p + 1], 0.f);
            }
        }
#pragma unroll
        for (int kk = 0; kk < 8; ++kk) {
            const float* wr = W2 + (size_t)(k0 + kk) * 64 + c0;
            float4 w0 = *(const float4*)wr;
            float4 w1 = *(const float4*)(wr + 4);
            const float* wf0 = (const float*)&w0;
            const float* wf1 = (const float*)&w1;
#pragma unroll
            for (int i = 0; i < 4; ++i) {
                float xs = xf[i][kk];
#pragma unroll
                for (int j = 0; j < 4; ++j) {
                    acc[i][j]     = fmaf(xs, wf0[j], acc[i][j]);
                    acc[i][j + 4] = fmaf(xs, wf1[j], acc[i][j + 4]);
                }
            }
        }
    }
#pragma unroll
    for (int i = 0; i < 4; ++i) {
        int r = r0 + i;
        if (r >= n) continue;
        float s = dinv[r];
        HV8 o;
#pragma unroll
        for (int j = 0; j < 8; ++j) o.h[j] = __float2half(acc[i][j] * s);
        *(uint4*)(Hh2 + (size_t)r * 64 + c0) = o.u;
    }
}

// ---------- layer-2 gather (64-d fp16) + FC, eighth-wave half8 ----------
__global__ __launch_bounds__(256) void k_gather_fc(const __half* __restrict__ Hs,
                                                   const float* __restrict__ dinv,
                                                   const int* __restrict__ row_ptr,
                                                   const int* __restrict__ col,
                                                   const float* __restrict__ b2,
                                                   const float* __restrict__ Wfc,
                                                   const float* __restrict__ bfc,
                                                   float* __restrict__ out, int n) {
    int wave = threadIdx.x >> 6;
    int lane = threadIdx.x & 63;
    int oi = lane >> 3, ol = lane & 7;
    float wrow[10];
#pragma unroll
    for (int j = 0; j < 10; ++j) wrow[j] = Wfc[lane * 10 + j];
    float b2c = b2[lane];

    int node = blockIdx.x * 4 + wave;
    if (node >= n) return;
    int beg = row_ptr[node], end = row_ptr[node + 1];
    int deg = end - beg;

    float acc[8];
#pragma unroll
    for (int v = 0; v < 8; ++v) acc[v] = 0.f;

    for (int base = 0; base < deg; base += 64) {
        int m = deg - base; if (m > 64) m = 64;
        int cl = (lane < m) ? col[beg + base + lane] : 0;
        int j = 0;
        for (; j + 16 <= m; j += 16) {
            int s0 = __shfl(cl, j + oi);
            int s1 = __shfl(cl, j + 8 + oi);
            HV8 u0, u1;
            u0.u = *(const uint4*)(Hs + (size_t)s0 * 64 + ol * 8);
            u1.u = *(const uint4*)(Hs + (size_t)s1 * 64 + ol * 8);
            acc8(acc, u0, 1.f); acc8(acc, u1, 1.f);
        }
        for (; j < m; j += 8) {
            int jj = j + oi;
            bool ok = jj < m;
            int s = __shfl(cl, ok ? jj : j);
            HV8 u; u.u = *(const uint4*)(Hs + (size_t)s * 64 + ol * 8);
            acc8(acc, u, ok ? 1.f : 0.f);
        }
    }
#pragma unroll
    for (int v = 0; v < 8; ++v) {
        acc[v] += __shfl_xor(acc[v], 32);
        acc[v] += __shfl_xor(acc[v], 16);
        acc[v] += __shfl_xor(acc[v], 8);
    }
    int srcl = lane >> 3;
    float vals[8];
#pragma unroll
    for (int v = 0; v < 8; ++v) vals[v] = __shfl(acc[v], srcl);
    int e = lane & 7;
    float aggv = vals[0];
#pragma unroll
    for (int v = 1; v < 8; ++v) aggv = (e == v) ? vals[v] : aggv;

    float selfv = __half2float(Hs[(size_t)node * 64 + lane]);
    float v = fmaxf((aggv + selfv) * dinv[node] + b2c, 0.f);
    float p[10];
#pragma unroll
    for (int j = 0; j < 10; ++j) p[j] = v * wrow[j];
#pragma unroll
    for (int off = 32; off > 0; off >>= 1)
#pragma unroll
        for (int j = 0; j < 10; ++j) p[j] += __shfl_xor(p[j], off);
    if (lane == 0) {
        float* o = out + (size_t)node * 10;
#pragma unroll
        for (int j = 0; j < 10; ++j) o[j] = p[j] + bfc[j];
    }
}

static inline int cdiv(long long a, int b) { return (int)((a + b - 1) / b); }

extern "C" void kernel_launch(void* const* d_in, const int* in_sizes, int n_in,
                              void* d_out, int out_size, void* d_ws, size_t ws_size,
                              hipStream_t stream) {
    const float* x   = (const float*)d_in[0];
    const int*   ei  = (const int*)d_in[1];
    const float* W1  = (const float*)d_in[2];
    const float* b1  = (const float*)d_in[3];
    const float* W2  = (const float*)d_in[4];
    const float* b2  = (const float*)d_in[5];
    const float* Wfc = (const float*)d_in[6];
    const float* bfc = (const float*)d_in[7];
    float* out = (float*)d_out;

    const int N = in_sizes[0] / 128;   // 100000
    const int E = in_sizes[1] / 2;     // 1600000
    const int* src = ei;
    const int* dst = ei + E;

    char* ws = (char*)d_ws;
    size_t off = 0;
    auto alloc = [&](size_t bytes) { void* p = ws + off; off = (off + bytes + 255) & ~(size_t)255; return p; };
    float*    dinv       = (float*)   alloc((size_t)N * 4);
    int*      row_ptr    = (int*)     alloc((size_t)(N + 1) * 4);
    int*      gcursor    = (int*)     alloc((size_t)NB * 4);
    int*      bucketBase = (int*)     alloc((size_t)NB * 4);
    unsigned* ebuf       = (unsigned*)alloc((size_t)NB * BCAP * 4);
    int*      col        = (int*)     alloc((size_t)E * 4);
    __half*   Hh1        = (__half*)  alloc((size_t)N * 128 * 2);
    __half*   Ah1        = (__half*)  alloc((size_t)N * 128 * 2);
    __half*   Hh2        = (__half*)  alloc((size_t)N * 64 * 2);

    // B1: bucket scatter (cursors zeroed first)
    hipMemsetAsync(gcursor, 0, (size_t)NB * 4, stream);
    k_bucket_scatter<<<112, 256, 0, stream>>>(src, dst, E, gcursor, ebuf);
    k_bucket_scan<<<1, 256, 0, stream>>>(gcursor, bucketBase);

    // B2 (CSR build per bucket) | GEMM1, interleaved 1:8
    k_csr_gemm1<<<NB * 9, 256, 0, stream>>>(ebuf, gcursor, bucketBase,
                                            row_ptr, col, dinv, N,
                                            x, W1, Hh1, N);

    // layer 1 aggregate (dinv[src] folded into gather weights)
    k_gather128<<<cdiv(N, 4), 256, 0, stream>>>(Hh1, dinv, row_ptr, col, Ah1, N);

    // layer 2 transform then aggregate+FC (writes d_out directly)
    k_gemm2<<<cdiv(N, 128), 256, 0, stream>>>(Ah1, W2, b1, dinv, Hh2, N);
    k_gather_fc<<<cdiv(N, 4), 256, 0, stream>>>(Hh2, dinv, row_ptr, col,
                                                b2, Wfc, bfc, out, N);
}

// Round 8
// 419.959 us; speedup vs baseline: 1.5489x; 1.1672x over previous
//
#include <hip/hip_runtime.h>
#include <hip/hip_fp16.h>

// GCN 2-layer + FC. Round 8: chunked 3-phase bucket scatter (per-block LDS
// binning, one cursor atomic per block-bucket, coalesced copy-out) interleaved
// 1:4 with GEMM1; standalone per-bucket CSR build (self-computed base);
// fp16 gathers unchanged.

static constexpr int NB    = 196;   // buckets = ceil(100000/512)
static constexpr int NPB   = 512;   // nodes per bucket
static constexpr int BCAP  = 9216;  // per-bucket capacity (mean 8192 + 11 sigma)
static constexpr int CHUNK = 4096;  // edges per scatter block

union HV8 { uint4 u; __half2 h2[4]; __half h[8]; };

__device__ inline void acc8(float* a, const HV8& v, float w) {
#pragma unroll
    for (int i = 0; i < 4; ++i) {
        float2 f = __half22float2(v.h2[i]);
        a[2 * i]     = fmaf(f.x, w, a[2 * i]);
        a[2 * i + 1] = fmaf(f.y, w, a[2 * i + 1]);
    }
}

// ---------- fused: {bucket scatter (1/5) | GEMM1 (4/5)} ----------
__global__ __launch_bounds__(256) void k_scatter_gemm1(
        const int* __restrict__ src, const int* __restrict__ dst, int E,
        int* __restrict__ gcursor, unsigned* __restrict__ ebuf,
        const float* __restrict__ X, const float* __restrict__ W,
        __half* __restrict__ Hh, int n) {
    int q = blockIdx.x / 5, r5 = blockIdx.x % 5;
    if (r5 == 0) {
        // ---- scatter role: chunk q of CHUNK edges ----
        __shared__ int hist[NB];
        __shared__ int lofs[NB];
        __shared__ int gbase[NB];
        __shared__ int lcur[NB];
        __shared__ int scanv[256];
        __shared__ unsigned pkbuf[CHUNK];          // 16 KB
        __shared__ unsigned char bbuf[CHUNK];      // 4 KB
        int tid = threadIdx.x;
        long long e0 = (long long)q * CHUNK;
        if (e0 >= E) return;
        int m = (int)(((long long)E - e0 < CHUNK) ? (E - e0) : CHUNK);

        for (int i = tid; i < NB; i += 256) hist[i] = 0;
        __syncthreads();

        unsigned pk[16]; int bk[16];
#pragma unroll
        for (int i = 0; i < 16; ++i) {
            int idx = i * 256 + tid;
            bool ok = idx < m;
            long long e = e0 + idx;
            int d = ok ? dst[e] : 0;
            int s = ok ? src[e] : 0;
            bk[i] = ok ? (d >> 9) : -1;
            pk[i] = ((unsigned)(d & 511) << 17) | (unsigned)s;
            if (ok) atomicAdd(&hist[bk[i]], 1);
        }
        __syncthreads();
        // exclusive scan of hist[196] via 256-wide inclusive scan
        int v = (tid < NB) ? hist[tid] : 0;
        scanv[tid] = v;
        __syncthreads();
        for (int off = 1; off < 256; off <<= 1) {
            int add = (tid >= off) ? scanv[tid - off] : 0;
            __syncthreads();
            scanv[tid] += add;
            __syncthreads();
        }
        if (tid < NB) {
            int ex = scanv[tid] - v;
            lofs[tid] = ex;
            lcur[tid] = ex;
            gbase[tid] = (v > 0) ? atomicAdd(&gcursor[tid], v) : 0;
        }
        __syncthreads();
        // slot-scatter into LDS
#pragma unroll
        for (int i = 0; i < 16; ++i) {
            if (bk[i] >= 0) {
                int slot = atomicAdd(&lcur[bk[i]], 1);
                pkbuf[slot] = pk[i];
                bbuf[slot] = (unsigned char)bk[i];
            }
        }
        __syncthreads();
        // coalesced copy-out: consecutive slots -> consecutive global dests
        for (int i = tid; i < m; i += 256) {
            int b = bbuf[i];
            int rel = gbase[b] + (i - lofs[b]);
            if (rel < BCAP) ebuf[(size_t)b * BCAP + rel] = pkbuf[i];
        }
        return;
    }
    // ---- GEMM1 role: Hh = fp16(X @ W), unscaled; 4x8 micro-tile ----
    int bid = q * 4 + (r5 - 1);
    int t = threadIdx.x;
    int tc = t & 15, tr = t >> 4;
    int c0 = tc * 8;
    int r0 = bid * 64 + tr * 4;
    if (r0 >= n + 3 && r0 >= n) { }

    const float* xp[4];
#pragma unroll
    for (int i = 0; i < 4; ++i) {
        int rr = r0 + i;
        xp[i] = X + (size_t)(rr < n ? rr : 0) * 128;
    }
    float acc[4][8];
#pragma unroll
    for (int i = 0; i < 4; ++i)
#pragma unroll
        for (int j = 0; j < 8; ++j) acc[i][j] = 0.f;

    for (int k0 = 0; k0 < 128; k0 += 4) {
        float4 xv[4];
#pragma unroll
        for (int i = 0; i < 4; ++i) xv[i] = *(const float4*)(xp[i] + k0);
        float4 w0[4], w1[4];
#pragma unroll
        for (int kk = 0; kk < 4; ++kk) {
            const float* wr = W + (size_t)(k0 + kk) * 128 + c0;
            w0[kk] = *(const float4*)wr;
            w1[kk] = *(const float4*)(wr + 4);
        }
#pragma unroll
        for (int kk = 0; kk < 4; ++kk) {
            const float* wf0 = (const float*)&w0[kk];
            const float* wf1 = (const float*)&w1[kk];
#pragma unroll
            for (int i = 0; i < 4; ++i) {
                float xs = ((const float*)&xv[i])[kk];
#pragma unroll
                for (int j = 0; j < 4; ++j) {
                    acc[i][j]     = fmaf(xs, wf0[j], acc[i][j]);
                    acc[i][j + 4] = fmaf(xs, wf1[j], acc[i][j + 4]);
                }
            }
        }
    }
#pragma unroll
    for (int i = 0; i < 4; ++i) {
        int rr = r0 + i;
        if (rr >= n) continue;
        HV8 o;
#pragma unroll
        for (int j = 0; j < 8; ++j) o.h[j] = __float2half(acc[i][j]);
        *(uint4*)(Hh + (size_t)rr * 128 + c0) = o.u;
    }
}

// ---------- per-bucket CSR build (196 blocks; self-computed base) ----------
__global__ __launch_bounds__(256) void k_csr_build(
        const unsigned* __restrict__ ebuf, const int* __restrict__ gcursor,
        int* __restrict__ row_ptr, int* __restrict__ col,
        float* __restrict__ dinv, int N_) {
    __shared__ int hist[NPB];
    __shared__ int scanv[256];
    __shared__ int rp[NPB];
    __shared__ int reds[256];
    int tid = threadIdx.x;
    int b = blockIdx.x;

    // base = sum_{i<b} min(gcursor[i], BCAP)
    int rv = (tid < NB && tid < b) ? min(gcursor[tid], BCAP) : 0;
    reds[tid] = rv;
    __syncthreads();
    for (int off = 128; off > 0; off >>= 1) {
        if (tid < off) reds[tid] += reds[tid + off];
        __syncthreads();
    }
    int base = reds[0];
    __syncthreads();

    for (int i = tid; i < NPB; i += 256) hist[i] = 0;
    __syncthreads();
    int cntb = min(gcursor[b], BCAP);
    const unsigned* seg = ebuf + (size_t)b * BCAP;
    for (int i = tid; i < cntb; i += 256)
        atomicAdd(&hist[seg[i] >> 17], 1);
    __syncthreads();
    // exclusive scan of hist[512]: 2 elems/thread
    int a0 = hist[2 * tid], a1 = hist[2 * tid + 1];
    int s = a0 + a1;
    scanv[tid] = s;
    __syncthreads();
    for (int off = 1; off < 256; off <<= 1) {
        int add = (tid >= off) ? scanv[tid - off] : 0;
        __syncthreads();
        scanv[tid] += add;
        __syncthreads();
    }
    int excl = scanv[tid] - s;
    rp[2 * tid] = excl;
    rp[2 * tid + 1] = excl + a0;
    __syncthreads();
    int node0 = b * NPB;
    for (int i = tid; i < NPB; i += 256) {
        int node = node0 + i;
        if (node < N_) {
            row_ptr[node] = base + rp[i];
            dinv[node] = rsqrtf((float)(hist[i] + 1));
        }
    }
    if (tid == 0 && b == NB - 1) row_ptr[N_] = base + cntb;
    __syncthreads();
    for (int i = tid; i < NPB; i += 256) rp[i] += base;   // rp -> global cursor
    __syncthreads();
    for (int i = tid; i < cntb; i += 256) {
        unsigned pk = seg[i];
        int pos = atomicAdd(&rp[pk >> 17], 1);
        col[pos] = (int)(pk & 0x1FFFFu);
    }
}

// ---------- layer-1 gather (128-d fp16), quarter-wave half8, dinv[src] weight ----------
__global__ __launch_bounds__(256) void k_gather128(const __half* __restrict__ Hs,
                                                   const float* __restrict__ dinv,
                                                   const int* __restrict__ row_ptr,
                                                   const int* __restrict__ col,
                                                   __half* __restrict__ outh, int n) {
    int wave = threadIdx.x >> 6;
    int lane = threadIdx.x & 63;
    int qi = lane >> 4, ql = lane & 15;
    int node = blockIdx.x * 4 + wave;
    if (node >= n) return;
    int beg = row_ptr[node], end = row_ptr[node + 1];
    int deg = end - beg;

    float acc[8];
#pragma unroll
    for (int v = 0; v < 8; ++v) acc[v] = 0.f;

    for (int base = 0; base < deg; base += 64) {
        int m = deg - base; if (m > 64) m = 64;
        int cl = (lane < m) ? col[beg + base + lane] : 0;
        int j = 0;
        for (; j + 16 <= m; j += 16) {
            int s0 = __shfl(cl, j + 0  + qi);
            int s1 = __shfl(cl, j + 4  + qi);
            int s2 = __shfl(cl, j + 8  + qi);
            int s3 = __shfl(cl, j + 12 + qi);
            float w0 = dinv[s0], w1 = dinv[s1], w2 = dinv[s2], w3 = dinv[s3];
            HV8 u0, u1, u2, u3;
            u0.u = *(const uint4*)(Hs + (size_t)s0 * 128 + ql * 8);
            u1.u = *(const uint4*)(Hs + (size_t)s1 * 128 + ql * 8);
            u2.u = *(const uint4*)(Hs + (size_t)s2 * 128 + ql * 8);
            u3.u = *(const uint4*)(Hs + (size_t)s3 * 128 + ql * 8);
            acc8(acc, u0, w0); acc8(acc, u1, w1);
            acc8(acc, u2, w2); acc8(acc, u3, w3);
        }
        for (; j < m; j += 4) {
            int jj = j + qi;
            bool ok = jj < m;
            int s = __shfl(cl, ok ? jj : j);
            float w = ok ? dinv[s] : 0.f;
            HV8 u; u.u = *(const uint4*)(Hs + (size_t)s * 128 + ql * 8);
            acc8(acc, u, w);
        }
    }
#pragma unroll
    for (int v = 0; v < 8; ++v) {
        acc[v] += __shfl_xor(acc[v], 32);
        acc[v] += __shfl_xor(acc[v], 16);
    }
    if (qi == 0) {
        HV8 su; su.u = *(const uint4*)(Hs + (size_t)node * 128 + ql * 8);
        float dn = dinv[node];
        HV8 o;
#pragma unroll
        for (int i = 0; i < 4; ++i) {
            float2 f = __half22float2(su.h2[i]);
            o.h[2 * i]     = __float2half((acc[2 * i]     + dn * f.x) * dn);
            o.h[2 * i + 1] = __float2half((acc[2 * i + 1] + dn * f.y) * dn);
        }
        *(uint4*)(outh + (size_t)node * 128 + ql * 8) = o.u;
    }
}

// ---------- GEMM2: Hh2 = fp16((relu(f32(A)+b1) @ W2) * dinv); A fp16 ----------
__global__ __launch_bounds__(256) void k_gemm2(const __half* __restrict__ A,
                                               const float* __restrict__ W2,
                                               const float* __restrict__ b1,
                                               const float* __restrict__ dinv,
                                               __half* __restrict__ Hh2, int n) {
    int t = threadIdx.x;
    int tc = t & 7, tr = t >> 3;
    int c0 = tc * 8;
    int r0 = blockIdx.x * 128 + tr * 4;

    const __half* xp[4];
#pragma unroll
    for (int i = 0; i < 4; ++i) {
        int r = r0 + i;
        xp[i] = A + (size_t)(r < n ? r : 0) * 128;
    }
    float acc[4][8];
#pragma unroll
    for (int i = 0; i < 4; ++i)
#pragma unroll
        for (int j = 0; j < 8; ++j) acc[i][j] = 0.f;

    for (int k0 = 0; k0 < 128; k0 += 8) {
        float bb[8];
#pragma unroll
        for (int p = 0; p < 8; ++p) bb[p] = b1[k0 + p];
        float xf[4][8];
#pragma unroll
        for (int i = 0; i < 4; ++i) {
            HV8 u; u.u = *(const uint4*)(xp[i] + k0);
#pragma unroll
            for (int p = 0; p < 4; ++p) {
                float2 f = __half22float2(u.h2[p]);
                xf[i][2 * p]     = fmaxf(f.x + bb[2 * p], 0.f);
                xf[i][2 * p + 1] = fmaxf(f.y + bb[2 * p + 1], 0.f);
            }
        }
#pragma unroll
        for (int kk = 0; kk < 8; ++kk) {
            const float* wr = W2 + (size_t)(k0 + kk) * 64 + c0;
            float4 w0 = *(const float4*)wr;
            float4 w1 = *(const float4*)(wr + 4);
            const float* wf0 = (const float*)&w0;
            const float* wf1 = (const float*)&w1;
#pragma unroll
            for (int i = 0; i < 4; ++i) {
                float xs = xf[i][kk];
#pragma unroll
                for (int j = 0; j < 4; ++j) {
                    acc[i][j]     = fmaf(xs, wf0[j], acc[i][j]);
                    acc[i][j + 4] = fmaf(xs, wf1[j], acc[i][j + 4]);
                }
            }
        }
    }
#pragma unroll
    for (int i = 0; i < 4; ++i) {
        int r = r0 + i;
        if (r >= n) continue;
        float s = dinv[r];
        HV8 o;
#pragma unroll
        for (int j = 0; j < 8; ++j) o.h[j] = __float2half(acc[i][j] * s);
        *(uint4*)(Hh2 + (size_t)r * 64 + c0) = o.u;
    }
}

// ---------- layer-2 gather (64-d fp16) + FC, eighth-wave half8 ----------
__global__ __launch_bounds__(256) void k_gather_fc(const __half* __restrict__ Hs,
                                                   const float* __restrict__ dinv,
                                                   const int* __restrict__ row_ptr,
                                                   const int* __restrict__ col,
                                                   const float* __restrict__ b2,
                                                   const float* __restrict__ Wfc,
                                                   const float* __restrict__ bfc,
                                                   float* __restrict__ out, int n) {
    int wave = threadIdx.x >> 6;
    int lane = threadIdx.x & 63;
    int oi = lane >> 3, ol = lane & 7;
    float wrow[10];
#pragma unroll
    for (int j = 0; j < 10; ++j) wrow[j] = Wfc[lane * 10 + j];
    float b2c = b2[lane];

    int node = blockIdx.x * 4 + wave;
    if (node >= n) return;
    int beg = row_ptr[node], end = row_ptr[node + 1];
    int deg = end - beg;

    float acc[8];
#pragma unroll
    for (int v = 0; v < 8; ++v) acc[v] = 0.f;

    for (int base = 0; base < deg; base += 64) {
        int m = deg - base; if (m > 64) m = 64;
        int cl = (lane < m) ? col[beg + base + lane] : 0;
        int j = 0;
        for (; j + 16 <= m; j += 16) {
            int s0 = __shfl(cl, j + oi);
            int s1 = __shfl(cl, j + 8 + oi);
            HV8 u0, u1;
            u0.u = *(const uint4*)(Hs + (size_t)s0 * 64 + ol * 8);
            u1.u = *(const uint4*)(Hs + (size_t)s1 * 64 + ol * 8);
            acc8(acc, u0, 1.f); acc8(acc, u1, 1.f);
        }
        for (; j < m; j += 8) {
            int jj = j + oi;
            bool ok = jj < m;
            int s = __shfl(cl, ok ? jj : j);
            HV8 u; u.u = *(const uint4*)(Hs + (size_t)s * 64 + ol * 8);
            acc8(acc, u, ok ? 1.f : 0.f);
        }
    }
#pragma unroll
    for (int v = 0; v < 8; ++v) {
        acc[v] += __shfl_xor(acc[v], 32);
        acc[v] += __shfl_xor(acc[v], 16);
        acc[v] += __shfl_xor(acc[v], 8);
    }
    int srcl = lane >> 3;
    float vals[8];
#pragma unroll
    for (int v = 0; v < 8; ++v) vals[v] = __shfl(acc[v], srcl);
    int e = lane & 7;
    float aggv = vals[0];
#pragma unroll
    for (int v = 1; v < 8; ++v) aggv = (e == v) ? vals[v] : aggv;

    float selfv = __half2float(Hs[(size_t)node * 64 + lane]);
    float v = fmaxf((aggv + selfv) * dinv[node] + b2c, 0.f);
    float p[10];
#pragma unroll
    for (int j = 0; j < 10; ++j) p[j] = v * wrow[j];
#pragma unroll
    for (int off = 32; off > 0; off >>= 1)
#pragma unroll
        for (int j = 0; j < 10; ++j) p[j] += __shfl_xor(p[j], off);
    if (lane == 0) {
        float* o = out + (size_t)node * 10;
#pragma unroll
        for (int j = 0; j < 10; ++j) o[j] = p[j] + bfc[j];
    }
}

static inline int cdiv(long long a, int b) { return (int)((a + b - 1) / b); }

extern "C" void kernel_launch(void* const* d_in, const int* in_sizes, int n_in,
                              void* d_out, int out_size, void* d_ws, size_t ws_size,
                              hipStream_t stream) {
    const float* x   = (const float*)d_in[0];
    const int*   ei  = (const int*)d_in[1];
    const float* W1  = (const float*)d_in[2];
    const float* b1  = (const float*)d_in[3];
    const float* W2  = (const float*)d_in[4];
    const float* b2  = (const float*)d_in[5];
    const float* Wfc = (const float*)d_in[6];
    const float* bfc = (const float*)d_in[7];
    float* out = (float*)d_out;

    const int N = in_sizes[0] / 128;   // 100000
    const int E = in_sizes[1] / 2;     // 1600000
    const int* src = ei;
    const int* dst = ei + E;

    char* ws = (char*)d_ws;
    size_t off = 0;
    auto alloc = [&](size_t bytes) { void* p = ws + off; off = (off + bytes + 255) & ~(size_t)255; return p; };
    float*    dinv    = (float*)   alloc((size_t)N * 4);
    int*      row_ptr = (int*)     alloc((size_t)(N + 1) * 4);
    int*      gcursor = (int*)     alloc((size_t)NB * 4);
    unsigned* ebuf    = (unsigned*)alloc((size_t)NB * BCAP * 4);
    int*      col     = (int*)     alloc((size_t)E * 4);
    __half*   Hh1     = (__half*)  alloc((size_t)N * 128 * 2);
    __half*   Ah1     = (__half*)  alloc((size_t)N * 128 * 2);
    __half*   Hh2     = (__half*)  alloc((size_t)N * 64 * 2);

    hipMemsetAsync(gcursor, 0, (size_t)NB * 4, stream);

    // fused {scatter | GEMM1}: 1:4 interleave
    const int scatterChunks = cdiv(E, CHUNK);             // 391
    const int gemmBlocks = cdiv(N, 64);                   // 1563
    const int groups = max(scatterChunks, cdiv(gemmBlocks, 4));
    k_scatter_gemm1<<<groups * 5, 256, 0, stream>>>(
        src, dst, E, gcursor, ebuf, x, W1, Hh1, N);

    // per-bucket CSR build (row_ptr, col, dinv)
    k_csr_build<<<NB, 256, 0, stream>>>(ebuf, gcursor, row_ptr, col, dinv, N);

    // layer 1 aggregate (dinv[src] folded into gather weights)
    k_gather128<<<cdiv(N, 4), 256, 0, stream>>>(Hh1, dinv, row_ptr, col, Ah1, N);

    // layer 2 transform then aggregate+FC (writes d_out directly)
    k_gemm2<<<cdiv(N, 128), 256, 0, stream>>>(Ah1, W2, b1, dinv, Hh2, N);
    k_gather_fc<<<cdiv(N, 4), 256, 0, stream>>>(Hh2, dinv, row_ptr, col,
                                                b2, Wfc, bfc, out, N);
}

// Round 9
// 414.898 us; speedup vs baseline: 1.5678x; 1.0122x over previous
//
#include <hip/hip_runtime.h>
#include <hip/hip_fp16.h>

// GCN 2-layer + FC. Round 9: standalone chunked scatter; {csr_build | GEMM1}
// fused 1:8 (CSR's 6KB LDS doesn't throttle GEMM occupancy); masked-uniform
// gather loops (constant loads-in-flight, no serialized tail).

static constexpr int NB    = 196;   // buckets = ceil(100000/512)
static constexpr int NPB   = 512;   // nodes per bucket
static constexpr int BCAP  = 9216;  // per-bucket capacity (mean 8192 + 11 sigma)
static constexpr int CHUNK = 4096;  // edges per scatter block

union HV8 { uint4 u; __half2 h2[4]; __half h[8]; };

__device__ inline void acc8(float* a, const HV8& v, float w) {
#pragma unroll
    for (int i = 0; i < 4; ++i) {
        float2 f = __half22float2(v.h2[i]);
        a[2 * i]     = fmaf(f.x, w, a[2 * i]);
        a[2 * i + 1] = fmaf(f.y, w, a[2 * i + 1]);
    }
}

// ---------- chunked 3-phase bucket scatter ----------
__global__ __launch_bounds__(256) void k_scatter(
        const int* __restrict__ src, const int* __restrict__ dst, int E,
        int* __restrict__ gcursor, unsigned* __restrict__ ebuf) {
    __shared__ int hist[NB];
    __shared__ int lofs[NB];
    __shared__ int gbase[NB];
    __shared__ int lcur[NB];
    __shared__ int scanv[256];
    __shared__ unsigned pkbuf[CHUNK];          // 16 KB
    __shared__ unsigned short bbuf[CHUNK];     // 8 KB
    int tid = threadIdx.x;
    long long e0 = (long long)blockIdx.x * CHUNK;
    if (e0 >= E) return;
    int m = (int)(((long long)E - e0 < CHUNK) ? (E - e0) : CHUNK);

    for (int i = tid; i < NB; i += 256) hist[i] = 0;
    __syncthreads();

    unsigned pk[16]; int bk[16];
#pragma unroll
    for (int i = 0; i < 16; ++i) {
        int idx = i * 256 + tid;
        bool ok = idx < m;
        long long e = e0 + idx;
        int d = ok ? dst[e] : 0;
        int s = ok ? src[e] : 0;
        bk[i] = ok ? (d >> 9) : -1;
        pk[i] = ((unsigned)(d & 511) << 17) | (unsigned)s;
        if (ok) atomicAdd(&hist[bk[i]], 1);
    }
    __syncthreads();
    int v = (tid < NB) ? hist[tid] : 0;
    scanv[tid] = v;
    __syncthreads();
    for (int off = 1; off < 256; off <<= 1) {
        int add = (tid >= off) ? scanv[tid - off] : 0;
        __syncthreads();
        scanv[tid] += add;
        __syncthreads();
    }
    if (tid < NB) {
        int ex = scanv[tid] - v;
        lofs[tid] = ex;
        lcur[tid] = ex;
        gbase[tid] = (v > 0) ? atomicAdd(&gcursor[tid], v) : 0;
    }
    __syncthreads();
#pragma unroll
    for (int i = 0; i < 16; ++i) {
        if (bk[i] >= 0) {
            int slot = atomicAdd(&lcur[bk[i]], 1);
            pkbuf[slot] = pk[i];
            bbuf[slot] = (unsigned short)bk[i];
        }
    }
    __syncthreads();
    for (int i = tid; i < m; i += 256) {
        int b = bbuf[i];
        int rel = gbase[b] + (i - lofs[b]);
        if (rel < BCAP) ebuf[(size_t)b * BCAP + rel] = pkbuf[i];
    }
}

// ---------- fused: {per-bucket CSR build (1/9) | GEMM1 (8/9)} ----------
__global__ __launch_bounds__(256) void k_csr_gemm1(
        const unsigned* __restrict__ ebuf, const int* __restrict__ gcursor,
        int* __restrict__ row_ptr, int* __restrict__ col,
        float* __restrict__ dinv, int N_,
        const float* __restrict__ X, const float* __restrict__ W,
        __half* __restrict__ Hh, int n) {
    int q = blockIdx.x / 9, r = blockIdx.x % 9;
    if (r == 8) {
        // ---- CSR role for bucket q ----
        __shared__ int hist[NPB];
        __shared__ int scanv[256];
        __shared__ int rp[NPB];
        __shared__ int reds[256];
        int tid = threadIdx.x;
        int b = q;
        // base = sum_{i<b} min(gcursor[i], BCAP)
        int rv = (tid < NB && tid < b) ? min(gcursor[tid], BCAP) : 0;
        reds[tid] = rv;
        __syncthreads();
        for (int off = 128; off > 0; off >>= 1) {
            if (tid < off) reds[tid] += reds[tid + off];
            __syncthreads();
        }
        int base = reds[0];
        __syncthreads();

        for (int i = tid; i < NPB; i += 256) hist[i] = 0;
        __syncthreads();
        int cntb = min(gcursor[b], BCAP);
        const unsigned* seg = ebuf + (size_t)b * BCAP;
        for (int i = tid; i < cntb; i += 256)
            atomicAdd(&hist[seg[i] >> 17], 1);
        __syncthreads();
        int a0 = hist[2 * tid], a1 = hist[2 * tid + 1];
        int s = a0 + a1;
        scanv[tid] = s;
        __syncthreads();
        for (int off = 1; off < 256; off <<= 1) {
            int add = (tid >= off) ? scanv[tid - off] : 0;
            __syncthreads();
            scanv[tid] += add;
            __syncthreads();
        }
        int excl = scanv[tid] - s;
        rp[2 * tid] = excl;
        rp[2 * tid + 1] = excl + a0;
        __syncthreads();
        int node0 = b * NPB;
        for (int i = tid; i < NPB; i += 256) {
            int node = node0 + i;
            if (node < N_) {
                row_ptr[node] = base + rp[i];
                dinv[node] = rsqrtf((float)(hist[i] + 1));
            }
        }
        if (tid == 0 && b == NB - 1) row_ptr[N_] = base + cntb;
        __syncthreads();
        for (int i = tid; i < NPB; i += 256) rp[i] += base;
        __syncthreads();
        for (int i = tid; i < cntb; i += 256) {
            unsigned pk = seg[i];
            int pos = atomicAdd(&rp[pk >> 17], 1);
            col[pos] = (int)(pk & 0x1FFFFu);
        }
        return;
    }
    // ---- GEMM1 role: Hh = fp16(X @ W), unscaled; 4x8 micro-tile ----
    int bid = q * 8 + r;
    int t = threadIdx.x;
    int tc = t & 15, tr = t >> 4;
    int c0 = tc * 8;
    int r0 = bid * 64 + tr * 4;

    const float* xp[4];
#pragma unroll
    for (int i = 0; i < 4; ++i) {
        int rr = r0 + i;
        xp[i] = X + (size_t)(rr < n ? rr : 0) * 128;
    }
    float acc[4][8];
#pragma unroll
    for (int i = 0; i < 4; ++i)
#pragma unroll
        for (int j = 0; j < 8; ++j) acc[i][j] = 0.f;

    for (int k0 = 0; k0 < 128; k0 += 4) {
        float4 xv[4];
#pragma unroll
        for (int i = 0; i < 4; ++i) xv[i] = *(const float4*)(xp[i] + k0);
        float4 w0[4], w1[4];
#pragma unroll
        for (int kk = 0; kk < 4; ++kk) {
            const float* wr = W + (size_t)(k0 + kk) * 128 + c0;
            w0[kk] = *(const float4*)wr;
            w1[kk] = *(const float4*)(wr + 4);
        }
#pragma unroll
        for (int kk = 0; kk < 4; ++kk) {
            const float* wf0 = (const float*)&w0[kk];
            const float* wf1 = (const float*)&w1[kk];
#pragma unroll
            for (int i = 0; i < 4; ++i) {
                float xs = ((const float*)&xv[i])[kk];
#pragma unroll
                for (int j = 0; j < 4; ++j) {
                    acc[i][j]     = fmaf(xs, wf0[j], acc[i][j]);
                    acc[i][j + 4] = fmaf(xs, wf1[j], acc[i][j + 4]);
                }
            }
        }
    }
#pragma unroll
    for (int i = 0; i < 4; ++i) {
        int rr = r0 + i;
        if (rr >= n) continue;
        HV8 o;
#pragma unroll
        for (int j = 0; j < 8; ++j) o.h[j] = __float2half(acc[i][j]);
        *(uint4*)(Hh + (size_t)rr * 128 + c0) = o.u;
    }
}

// ---------- layer-1 gather (128-d fp16), quarter-wave, masked-uniform ----------
__global__ __launch_bounds__(256) void k_gather128(const __half* __restrict__ Hs,
                                                   const float* __restrict__ dinv,
                                                   const int* __restrict__ row_ptr,
                                                   const int* __restrict__ col,
                                                   __half* __restrict__ outh, int n) {
    int wave = threadIdx.x >> 6;
    int lane = threadIdx.x & 63;
    int qi = lane >> 4, ql = lane & 15;
    int node = blockIdx.x * 4 + wave;
    if (node >= n) return;
    int beg = row_ptr[node], end = row_ptr[node + 1];
    int deg = end - beg;

    float acc[8];
#pragma unroll
    for (int v = 0; v < 8; ++v) acc[v] = 0.f;

    for (int base = 0; base < deg; base += 64) {
        int m = deg - base; if (m > 64) m = 64;
        int cl = (lane < m) ? col[beg + base + lane] : 0;
        for (int j = 0; j < m; j += 16) {
            int j0 = j + qi, j1 = j + 4 + qi, j2 = j + 8 + qi, j3 = j + 12 + qi;
            int s0 = __shfl(cl, j0 < m ? j0 : j);
            int s1 = __shfl(cl, j1 < m ? j1 : j);
            int s2 = __shfl(cl, j2 < m ? j2 : j);
            int s3 = __shfl(cl, j3 < m ? j3 : j);
            float w0 = (j0 < m) ? dinv[s0] : 0.f;
            float w1 = (j1 < m) ? dinv[s1] : 0.f;
            float w2 = (j2 < m) ? dinv[s2] : 0.f;
            float w3 = (j3 < m) ? dinv[s3] : 0.f;
            HV8 u0, u1, u2, u3;
            u0.u = *(const uint4*)(Hs + (size_t)s0 * 128 + ql * 8);
            u1.u = *(const uint4*)(Hs + (size_t)s1 * 128 + ql * 8);
            u2.u = *(const uint4*)(Hs + (size_t)s2 * 128 + ql * 8);
            u3.u = *(const uint4*)(Hs + (size_t)s3 * 128 + ql * 8);
            acc8(acc, u0, w0); acc8(acc, u1, w1);
            acc8(acc, u2, w2); acc8(acc, u3, w3);
        }
    }
#pragma unroll
    for (int v = 0; v < 8; ++v) {
        acc[v] += __shfl_xor(acc[v], 32);
        acc[v] += __shfl_xor(acc[v], 16);
    }
    if (qi == 0) {
        HV8 su; su.u = *(const uint4*)(Hs + (size_t)node * 128 + ql * 8);
        float dn = dinv[node];
        HV8 o;
#pragma unroll
        for (int i = 0; i < 4; ++i) {
            float2 f = __half22float2(su.h2[i]);
            o.h[2 * i]     = __float2half((acc[2 * i]     + dn * f.x) * dn);
            o.h[2 * i + 1] = __float2half((acc[2 * i + 1] + dn * f.y) * dn);
        }
        *(uint4*)(outh + (size_t)node * 128 + ql * 8) = o.u;
    }
}

// ---------- GEMM2: Hh2 = fp16((relu(f32(A)+b1) @ W2) * dinv); A fp16 ----------
__global__ __launch_bounds__(256) void k_gemm2(const __half* __restrict__ A,
                                               const float* __restrict__ W2,
                                               const float* __restrict__ b1,
                                               const float* __restrict__ dinv,
                                               __half* __restrict__ Hh2, int n) {
    int t = threadIdx.x;
    int tc = t & 7, tr = t >> 3;
    int c0 = tc * 8;
    int r0 = blockIdx.x * 128 + tr * 4;

    const __half* xp[4];
#pragma unroll
    for (int i = 0; i < 4; ++i) {
        int r = r0 + i;
        xp[i] = A + (size_t)(r < n ? r : 0) * 128;
    }
    float acc[4][8];
#pragma unroll
    for (int i = 0; i < 4; ++i)
#pragma unroll
        for (int j = 0; j < 8; ++j) acc[i][j] = 0.f;

    for (int k0 = 0; k0 < 128; k0 += 8) {
        float bb[8];
#pragma unroll
        for (int p = 0; p < 8; ++p) bb[p] = b1[k0 + p];
        float xf[4][8];
#pragma unroll
        for (int i = 0; i < 4; ++i) {
            HV8 u; u.u = *(const uint4*)(xp[i] + k0);
#pragma unroll
            for (int p = 0; p < 4; ++p) {
                float2 f = __half22float2(u.h2[p]);
                xf[i][2 * p]     = fmaxf(f.x + bb[2 * p], 0.f);
                xf[i][2 * p + 1] = fmaxf(f.y + bb[2 * p + 1], 0.f);
            }
        }
#pragma unroll
        for (int kk = 0; kk < 8; ++kk) {
            const float* wr = W2 + (size_t)(k0 + kk) * 64 + c0;
            float4 w0 = *(const float4*)wr;
            float4 w1 = *(const float4*)(wr + 4);
            const float* wf0 = (const float*)&w0;
            const float* wf1 = (const float*)&w1;
#pragma unroll
            for (int i = 0; i < 4; ++i) {
                float xs = xf[i][kk];
#pragma unroll
                for (int j = 0; j < 4; ++j) {
                    acc[i][j]     = fmaf(xs, wf0[j], acc[i][j]);
                    acc[i][j + 4] = fmaf(xs, wf1[j], acc[i][j + 4]);
                }
            }
        }
    }
#pragma unroll
    for (int i = 0; i < 4; ++i) {
        int r = r0 + i;
        if (r >= n) continue;
        float s = dinv[r];
        HV8 o;
#pragma unroll
        for (int j = 0; j < 8; ++j) o.h[j] = __float2half(acc[i][j] * s);
        *(uint4*)(Hh2 + (size_t)r * 64 + c0) = o.u;
    }
}

// ---------- layer-2 gather (64-d fp16) + FC, eighth-wave, masked-uniform ----------
__global__ __launch_bounds__(256) void k_gather_fc(const __half* __restrict__ Hs,
                                                   const float* __restrict__ dinv,
                                                   const int* __restrict__ row_ptr,
                                                   const int* __restrict__ col,
                                                   const float* __restrict__ b2,
                                                   const float* __restrict__ Wfc,
                                                   const float* __restrict__ bfc,
                                                   float* __restrict__ out, int n) {
    int wave = threadIdx.x >> 6;
    int lane = threadIdx.x & 63;
    int oi = lane >> 3, ol = lane & 7;
    float wrow[10];
#pragma unroll
    for (int j = 0; j < 10; ++j) wrow[j] = Wfc[lane * 10 + j];
    float b2c = b2[lane];

    int node = blockIdx.x * 4 + wave;
    if (node >= n) return;
    int beg = row_ptr[node], end = row_ptr[node + 1];
    int deg = end - beg;

    float acc[8];
#pragma unroll
    for (int v = 0; v < 8; ++v) acc[v] = 0.f;

    for (int base = 0; base < deg; base += 64) {
        int m = deg - base; if (m > 64) m = 64;
        int cl = (lane < m) ? col[beg + base + lane] : 0;
        for (int j = 0; j < m; j += 16) {
            int j0 = j + oi, j1 = j + 8 + oi;
            int s0 = __shfl(cl, j0 < m ? j0 : j);
            int s1 = __shfl(cl, j1 < m ? j1 : j);
            float w0 = (j0 < m) ? 1.f : 0.f;
            float w1 = (j1 < m) ? 1.f : 0.f;
            HV8 u0, u1;
            u0.u = *(const uint4*)(Hs + (size_t)s0 * 64 + ol * 8);
            u1.u = *(const uint4*)(Hs + (size_t)s1 * 64 + ol * 8);
            acc8(acc, u0, w0); acc8(acc, u1, w1);
        }
    }
#pragma unroll
    for (int v = 0; v < 8; ++v) {
        acc[v] += __shfl_xor(acc[v], 32);
        acc[v] += __shfl_xor(acc[v], 16);
        acc[v] += __shfl_xor(acc[v], 8);
    }
    int srcl = lane >> 3;
    float vals[8];
#pragma unroll
    for (int v = 0; v < 8; ++v) vals[v] = __shfl(acc[v], srcl);
    int e = lane & 7;
    float aggv = vals[0];
#pragma unroll
    for (int v = 1; v < 8; ++v) aggv = (e == v) ? vals[v] : aggv;

    float selfv = __half2float(Hs[(size_t)node * 64 + lane]);
    float v = fmaxf((aggv + selfv) * dinv[node] + b2c, 0.f);
    float p[10];
#pragma unroll
    for (int j = 0; j < 10; ++j) p[j] = v * wrow[j];
#pragma unroll
    for (int off = 32; off > 0; off >>= 1)
#pragma unroll
        for (int j = 0; j < 10; ++j) p[j] += __shfl_xor(p[j], off);
    if (lane == 0) {
        float* o = out + (size_t)node * 10;
#pragma unroll
        for (int j = 0; j < 10; ++j) o[j] = p[j] + bfc[j];
    }
}

static inline int cdiv(long long a, int b) { return (int)((a + b - 1) / b); }

extern "C" void kernel_launch(void* const* d_in, const int* in_sizes, int n_in,
                              void* d_out, int out_size, void* d_ws, size_t ws_size,
                              hipStream_t stream) {
    const float* x   = (const float*)d_in[0];
    const int*   ei  = (const int*)d_in[1];
    const float* W1  = (const float*)d_in[2];
    const float* b1  = (const float*)d_in[3];
    const float* W2  = (const float*)d_in[4];
    const float* b2  = (const float*)d_in[5];
    const float* Wfc = (const float*)d_in[6];
    const float* bfc = (const float*)d_in[7];
    float* out = (float*)d_out;

    const int N = in_sizes[0] / 128;   // 100000
    const int E = in_sizes[1] / 2;     // 1600000
    const int* src = ei;
    const int* dst = ei + E;

    char* ws = (char*)d_ws;
    size_t off = 0;
    auto alloc = [&](size_t bytes) { void* p = ws + off; off = (off + bytes + 255) & ~(size_t)255; return p; };
    float*    dinv    = (float*)   alloc((size_t)N * 4);
    int*      row_ptr = (int*)     alloc((size_t)(N + 1) * 4);
    int*      gcursor = (int*)     alloc((size_t)NB * 4);
    unsigned* ebuf    = (unsigned*)alloc((size_t)NB * BCAP * 4);
    int*      col     = (int*)     alloc((size_t)E * 4);
    __half*   Hh1     = (__half*)  alloc((size_t)N * 128 * 2);
    __half*   Ah1     = (__half*)  alloc((size_t)N * 128 * 2);
    __half*   Hh2     = (__half*)  alloc((size_t)N * 64 * 2);

    hipMemsetAsync(gcursor, 0, (size_t)NB * 4, stream);

    // bucket scatter (standalone)
    k_scatter<<<cdiv(E, CHUNK), 256, 0, stream>>>(src, dst, E, gcursor, ebuf);

    // {CSR build | GEMM1} fused 1:8  (grid = NB*9 = 1764 covers 1563 GEMM blocks)
    k_csr_gemm1<<<NB * 9, 256, 0, stream>>>(ebuf, gcursor, row_ptr, col, dinv, N,
                                            x, W1, Hh1, N);

    // layer 1 aggregate (dinv[src] folded into gather weights)
    k_gather128<<<cdiv(N, 4), 256, 0, stream>>>(Hh1, dinv, row_ptr, col, Ah1, N);

    // layer 2 transform then aggregate+FC (writes d_out directly)
    k_gemm2<<<cdiv(N, 128), 256, 0, stream>>>(Ah1, W2, b1, dinv, Hh2, N);
    k_gather_fc<<<cdiv(N, 4), 256, 0, stream>>>(Hh2, dinv, row_ptr, col,
                                                b2, Wfc, bfc, out, N);
}

// Round 10
// 329.361 us; speedup vs baseline: 1.9749x; 1.2597x over previous
//
#include <hip/hip_runtime.h>
#include <hip/hip_fp16.h>

// GCN 2-layer + FC. Round 10: fp16 MFMA GEMMs (16x16x32_f16, fp32 acc).
// GEMM1: W1 staged fp16-transposed in LDS (pad 136), X converted in A-frag,
// M-tile 128. GEMM2: same, A already fp16 (bias+relu in fp16 fragment).
// CSR build stays fused 1:4 with GEMM1. Scatter + gathers unchanged.

static constexpr int NB    = 196;   // buckets = ceil(100000/512)
static constexpr int NPB   = 512;   // nodes per bucket
static constexpr int BCAP  = 9216;  // per-bucket capacity
static constexpr int CHUNK = 4096;  // edges per scatter block

typedef _Float16 f16x8 __attribute__((ext_vector_type(8)));
typedef float    f32x4 __attribute__((ext_vector_type(4)));

union HV8 { uint4 u; __half2 h2[4]; __half h[8]; };

__device__ inline void acc8(float* a, const HV8& v, float w) {
#pragma unroll
    for (int i = 0; i < 4; ++i) {
        float2 f = __half22float2(v.h2[i]);
        a[2 * i]     = fmaf(f.x, w, a[2 * i]);
        a[2 * i + 1] = fmaf(f.y, w, a[2 * i + 1]);
    }
}

// ---------- chunked 3-phase bucket scatter ----------
__global__ __launch_bounds__(256) void k_scatter(
        const int* __restrict__ src, const int* __restrict__ dst, int E,
        int* __restrict__ gcursor, unsigned* __restrict__ ebuf) {
    __shared__ int hist[NB];
    __shared__ int lofs[NB];
    __shared__ int gbase[NB];
    __shared__ int lcur[NB];
    __shared__ int scanv[256];
    __shared__ unsigned pkbuf[CHUNK];
    __shared__ unsigned short bbuf[CHUNK];
    int tid = threadIdx.x;
    long long e0 = (long long)blockIdx.x * CHUNK;
    if (e0 >= E) return;
    int m = (int)(((long long)E - e0 < CHUNK) ? (E - e0) : CHUNK);

    for (int i = tid; i < NB; i += 256) hist[i] = 0;
    __syncthreads();

    unsigned pk[16]; int bk[16];
#pragma unroll
    for (int i = 0; i < 16; ++i) {
        int idx = i * 256 + tid;
        bool ok = idx < m;
        long long e = e0 + idx;
        int d = ok ? dst[e] : 0;
        int s = ok ? src[e] : 0;
        bk[i] = ok ? (d >> 9) : -1;
        pk[i] = ((unsigned)(d & 511) << 17) | (unsigned)s;
        if (ok) atomicAdd(&hist[bk[i]], 1);
    }
    __syncthreads();
    int v = (tid < NB) ? hist[tid] : 0;
    scanv[tid] = v;
    __syncthreads();
    for (int off = 1; off < 256; off <<= 1) {
        int add = (tid >= off) ? scanv[tid - off] : 0;
        __syncthreads();
        scanv[tid] += add;
        __syncthreads();
    }
    if (tid < NB) {
        int ex = scanv[tid] - v;
        lofs[tid] = ex;
        lcur[tid] = ex;
        gbase[tid] = (v > 0) ? atomicAdd(&gcursor[tid], v) : 0;
    }
    __syncthreads();
#pragma unroll
    for (int i = 0; i < 16; ++i) {
        if (bk[i] >= 0) {
            int slot = atomicAdd(&lcur[bk[i]], 1);
            pkbuf[slot] = pk[i];
            bbuf[slot] = (unsigned short)bk[i];
        }
    }
    __syncthreads();
    for (int i = tid; i < m; i += 256) {
        int b = bbuf[i];
        int rel = gbase[b] + (i - lofs[b]);
        if (rel < BCAP) ebuf[(size_t)b * BCAP + rel] = pkbuf[i];
    }
}

// ---------- fused: {per-bucket CSR build (1/5) | MFMA GEMM1 (4/5)} ----------
union SharedU {
    _Float16 Wt[128][136];                                   // 34.8 KB
    struct { int hist[NPB]; int scanv[256]; int rp[NPB]; int reds[256]; } c;
};

__global__ __launch_bounds__(256) void k_csr_gemm1(
        const unsigned* __restrict__ ebuf, const int* __restrict__ gcursor,
        int* __restrict__ row_ptr, int* __restrict__ col,
        float* __restrict__ dinv, int N_,
        const float* __restrict__ X, const float* __restrict__ W,
        __half* __restrict__ Hh, int n) {
    __shared__ SharedU sh;
    int q = blockIdx.x / 5, r = blockIdx.x % 5;
    int tid = threadIdx.x;
    if (r == 4) {
        // ---- CSR role for bucket q ----
        int b = q;
        int rv = (tid < NB && tid < b) ? min(gcursor[tid], BCAP) : 0;
        sh.c.reds[tid] = rv;
        __syncthreads();
        for (int off = 128; off > 0; off >>= 1) {
            if (tid < off) sh.c.reds[tid] += sh.c.reds[tid + off];
            __syncthreads();
        }
        int base = sh.c.reds[0];
        __syncthreads();

        for (int i = tid; i < NPB; i += 256) sh.c.hist[i] = 0;
        __syncthreads();
        int cntb = min(gcursor[b], BCAP);
        const unsigned* seg = ebuf + (size_t)b * BCAP;
        for (int i = tid; i < cntb; i += 256)
            atomicAdd(&sh.c.hist[seg[i] >> 17], 1);
        __syncthreads();
        int a0 = sh.c.hist[2 * tid], a1 = sh.c.hist[2 * tid + 1];
        int s = a0 + a1;
        sh.c.scanv[tid] = s;
        __syncthreads();
        for (int off = 1; off < 256; off <<= 1) {
            int add = (tid >= off) ? sh.c.scanv[tid - off] : 0;
            __syncthreads();
            sh.c.scanv[tid] += add;
            __syncthreads();
        }
        int excl = sh.c.scanv[tid] - s;
        sh.c.rp[2 * tid] = excl;
        sh.c.rp[2 * tid + 1] = excl + a0;
        __syncthreads();
        int node0 = b * NPB;
        for (int i = tid; i < NPB; i += 256) {
            int node = node0 + i;
            if (node < N_) {
                row_ptr[node] = base + sh.c.rp[i];
                dinv[node] = rsqrtf((float)(sh.c.hist[i] + 1));
            }
        }
        if (tid == 0 && b == NB - 1) row_ptr[N_] = base + cntb;
        __syncthreads();
        for (int i = tid; i < NPB; i += 256) sh.c.rp[i] += base;
        __syncthreads();
        for (int i = tid; i < cntb; i += 256) {
            unsigned pk = seg[i];
            int pos = atomicAdd(&sh.c.rp[pk >> 17], 1);
            col[pos] = (int)(pk & 0x1FFFFu);
        }
        return;
    }
    // ---- GEMM1 role (MFMA): Hh = fp16(X @ W1), unscaled ----
    int bid = q * 4 + r;                       // 0..783
    for (int idx = tid; idx < 128 * 128; idx += 256) {
        int k = idx >> 7, c = idx & 127;
        sh.Wt[c][k] = (_Float16)W[idx];        // transpose: Wt[n][k]
    }
    __syncthreads();
    if (bid * 128 >= n) return;

    int wv = tid >> 6, l = tid & 63;
    int lr = l & 15, lq = l >> 4;
    int rowb = bid * 128 + wv * 32;            // wave's 32 rows (2 tiles)

    f32x4 acc[2][8];
#pragma unroll
    for (int rt = 0; rt < 2; ++rt)
#pragma unroll
        for (int ct = 0; ct < 8; ++ct) acc[rt][ct] = (f32x4){0.f, 0.f, 0.f, 0.f};

#pragma unroll
    for (int kt = 0; kt < 4; ++kt) {
        int kb = kt * 32 + lq * 8;
        f16x8 af[2];
#pragma unroll
        for (int rt = 0; rt < 2; ++rt) {
            int row = rowb + rt * 16 + lr;
            row = (row < n) ? row : (n - 1);
            const float* xr = X + (size_t)row * 128 + kb;
            float4 xa = *(const float4*)xr;
            float4 xb = *(const float4*)(xr + 4);
            f16x8 a;
            a[0] = (_Float16)xa.x; a[1] = (_Float16)xa.y;
            a[2] = (_Float16)xa.z; a[3] = (_Float16)xa.w;
            a[4] = (_Float16)xb.x; a[5] = (_Float16)xb.y;
            a[6] = (_Float16)xb.z; a[7] = (_Float16)xb.w;
            af[rt] = a;
        }
#pragma unroll
        for (int ct = 0; ct < 8; ++ct) {
            f16x8 bf = *(const f16x8*)&sh.Wt[ct * 16 + lr][kb];
            acc[0][ct] = __builtin_amdgcn_mfma_f32_16x16x32_f16(af[0], bf, acc[0][ct], 0, 0, 0);
            acc[1][ct] = __builtin_amdgcn_mfma_f32_16x16x32_f16(af[1], bf, acc[1][ct], 0, 0, 0);
        }
    }
    // epilogue: C layout col=lane&15, row=(lane>>4)*4+reg
#pragma unroll
    for (int rt = 0; rt < 2; ++rt)
#pragma unroll
        for (int j = 0; j < 4; ++j) {
            int row = rowb + rt * 16 + lq * 4 + j;
            if (row >= n) continue;
            __half* hr = Hh + (size_t)row * 128 + lr;
#pragma unroll
            for (int ct = 0; ct < 8; ++ct)
                hr[ct * 16] = __float2half(acc[rt][ct][j]);
        }
}

// ---------- layer-1 gather (128-d fp16), quarter-wave, masked-uniform ----------
__global__ __launch_bounds__(256) void k_gather128(const __half* __restrict__ Hs,
                                                   const float* __restrict__ dinv,
                                                   const int* __restrict__ row_ptr,
                                                   const int* __restrict__ col,
                                                   __half* __restrict__ outh, int n) {
    int wave = threadIdx.x >> 6;
    int lane = threadIdx.x & 63;
    int qi = lane >> 4, ql = lane & 15;
    int node = blockIdx.x * 4 + wave;
    if (node >= n) return;
    int beg = row_ptr[node], end = row_ptr[node + 1];
    int deg = end - beg;

    float acc[8];
#pragma unroll
    for (int v = 0; v < 8; ++v) acc[v] = 0.f;

    for (int base = 0; base < deg; base += 64) {
        int m = deg - base; if (m > 64) m = 64;
        int cl = (lane < m) ? col[beg + base + lane] : 0;
        for (int j = 0; j < m; j += 16) {
            int j0 = j + qi, j1 = j + 4 + qi, j2 = j + 8 + qi, j3 = j + 12 + qi;
            int s0 = __shfl(cl, j0 < m ? j0 : j);
            int s1 = __shfl(cl, j1 < m ? j1 : j);
            int s2 = __shfl(cl, j2 < m ? j2 : j);
            int s3 = __shfl(cl, j3 < m ? j3 : j);
            float w0 = (j0 < m) ? dinv[s0] : 0.f;
            float w1 = (j1 < m) ? dinv[s1] : 0.f;
            float w2 = (j2 < m) ? dinv[s2] : 0.f;
            float w3 = (j3 < m) ? dinv[s3] : 0.f;
            HV8 u0, u1, u2, u3;
            u0.u = *(const uint4*)(Hs + (size_t)s0 * 128 + ql * 8);
            u1.u = *(const uint4*)(Hs + (size_t)s1 * 128 + ql * 8);
            u2.u = *(const uint4*)(Hs + (size_t)s2 * 128 + ql * 8);
            u3.u = *(const uint4*)(Hs + (size_t)s3 * 128 + ql * 8);
            acc8(acc, u0, w0); acc8(acc, u1, w1);
            acc8(acc, u2, w2); acc8(acc, u3, w3);
        }
    }
#pragma unroll
    for (int v = 0; v < 8; ++v) {
        acc[v] += __shfl_xor(acc[v], 32);
        acc[v] += __shfl_xor(acc[v], 16);
    }
    if (qi == 0) {
        HV8 su; su.u = *(const uint4*)(Hs + (size_t)node * 128 + ql * 8);
        float dn = dinv[node];
        HV8 o;
#pragma unroll
        for (int i = 0; i < 4; ++i) {
            float2 f = __half22float2(su.h2[i]);
            o.h[2 * i]     = __float2half((acc[2 * i]     + dn * f.x) * dn);
            o.h[2 * i + 1] = __float2half((acc[2 * i + 1] + dn * f.y) * dn);
        }
        *(uint4*)(outh + (size_t)node * 128 + ql * 8) = o.u;
    }
}

// ---------- GEMM2 (MFMA): Hh2 = fp16((relu(A+b1) @ W2) * dinv), A fp16 ----------
__global__ __launch_bounds__(256) void k_gemm2(const __half* __restrict__ A,
                                               const float* __restrict__ W2,
                                               const float* __restrict__ b1,
                                               const float* __restrict__ dinv,
                                               __half* __restrict__ Hh2, int n) {
    __shared__ _Float16 Wt[64][136];           // [n][k], 17.4 KB
    __shared__ _Float16 b1h[128];
    int tid = threadIdx.x;
    for (int idx = tid; idx < 128 * 64; idx += 256) {
        int k = idx >> 6, c = idx & 63;
        Wt[c][k] = (_Float16)W2[idx];
    }
    if (tid < 128) b1h[tid] = (_Float16)b1[tid];
    __syncthreads();

    int bid = blockIdx.x;
    if (bid * 128 >= n) return;
    int wv = tid >> 6, l = tid & 63;
    int lr = l & 15, lq = l >> 4;
    int rowb = bid * 128 + wv * 32;

    f32x4 acc[2][4];
#pragma unroll
    for (int rt = 0; rt < 2; ++rt)
#pragma unroll
        for (int ct = 0; ct < 4; ++ct) acc[rt][ct] = (f32x4){0.f, 0.f, 0.f, 0.f};

#pragma unroll
    for (int kt = 0; kt < 4; ++kt) {
        int kb = kt * 32 + lq * 8;
        f16x8 bb = *(const f16x8*)&b1h[kb];
        f16x8 af[2];
#pragma unroll
        for (int rt = 0; rt < 2; ++rt) {
            int row = rowb + rt * 16 + lr;
            row = (row < n) ? row : (n - 1);
            f16x8 a = *(const f16x8*)(A + (size_t)row * 128 + kb);
            a = a + bb;
#pragma unroll
            for (int i = 0; i < 8; ++i)
                a[i] = (a[i] > (_Float16)0.f) ? a[i] : (_Float16)0.f;
            af[rt] = a;
        }
#pragma unroll
        for (int ct = 0; ct < 4; ++ct) {
            f16x8 bf = *(const f16x8*)&Wt[ct * 16 + lr][kb];
            acc[0][ct] = __builtin_amdgcn_mfma_f32_16x16x32_f16(af[0], bf, acc[0][ct], 0, 0, 0);
            acc[1][ct] = __builtin_amdgcn_mfma_f32_16x16x32_f16(af[1], bf, acc[1][ct], 0, 0, 0);
        }
    }
#pragma unroll
    for (int rt = 0; rt < 2; ++rt)
#pragma unroll
        for (int j = 0; j < 4; ++j) {
            int row = rowb + rt * 16 + lq * 4 + j;
            if (row >= n) continue;
            float dn = dinv[row];
            __half* hr = Hh2 + (size_t)row * 64 + lr;
#pragma unroll
            for (int ct = 0; ct < 4; ++ct)
                hr[ct * 16] = __float2half(acc[rt][ct][j] * dn);
        }
}

// ---------- layer-2 gather (64-d fp16) + FC, eighth-wave, masked-uniform ----------
__global__ __launch_bounds__(256) void k_gather_fc(const __half* __restrict__ Hs,
                                                   const float* __restrict__ dinv,
                                                   const int* __restrict__ row_ptr,
                                                   const int* __restrict__ col,
                                                   const float* __restrict__ b2,
                                                   const float* __restrict__ Wfc,
                                                   const float* __restrict__ bfc,
                                                   float* __restrict__ out, int n) {
    int wave = threadIdx.x >> 6;
    int lane = threadIdx.x & 63;
    int oi = lane >> 3, ol = lane & 7;
    float wrow[10];
#pragma unroll
    for (int j = 0; j < 10; ++j) wrow[j] = Wfc[lane * 10 + j];
    float b2c = b2[lane];

    int node = blockIdx.x * 4 + wave;
    if (node >= n) return;
    int beg = row_ptr[node], end = row_ptr[node + 1];
    int deg = end - beg;

    float acc[8];
#pragma unroll
    for (int v = 0; v < 8; ++v) acc[v] = 0.f;

    for (int base = 0; base < deg; base += 64) {
        int m = deg - base; if (m > 64) m = 64;
        int cl = (lane < m) ? col[beg + base + lane] : 0;
        for (int j = 0; j < m; j += 16) {
            int j0 = j + oi, j1 = j + 8 + oi;
            int s0 = __shfl(cl, j0 < m ? j0 : j);
            int s1 = __shfl(cl, j1 < m ? j1 : j);
            float w0 = (j0 < m) ? 1.f : 0.f;
            float w1 = (j1 < m) ? 1.f : 0.f;
            HV8 u0, u1;
            u0.u = *(const uint4*)(Hs + (size_t)s0 * 64 + ol * 8);
            u1.u = *(const uint4*)(Hs + (size_t)s1 * 64 + ol * 8);
            acc8(acc, u0, w0); acc8(acc, u1, w1);
        }
    }
#pragma unroll
    for (int v = 0; v < 8; ++v) {
        acc[v] += __shfl_xor(acc[v], 32);
        acc[v] += __shfl_xor(acc[v], 16);
        acc[v] += __shfl_xor(acc[v], 8);
    }
    int srcl = lane >> 3;
    float vals[8];
#pragma unroll
    for (int v = 0; v < 8; ++v) vals[v] = __shfl(acc[v], srcl);
    int e = lane & 7;
    float aggv = vals[0];
#pragma unroll
    for (int v = 1; v < 8; ++v) aggv = (e == v) ? vals[v] : aggv;

    float selfv = __half2float(Hs[(size_t)node * 64 + lane]);
    float v = fmaxf((aggv + selfv) * dinv[node] + b2c, 0.f);
    float p[10];
#pragma unroll
    for (int j = 0; j < 10; ++j) p[j] = v * wrow[j];
#pragma unroll
    for (int off = 32; off > 0; off >>= 1)
#pragma unroll
        for (int j = 0; j < 10; ++j) p[j] += __shfl_xor(p[j], off);
    if (lane == 0) {
        float* o = out + (size_t)node * 10;
#pragma unroll
        for (int j = 0; j < 10; ++j) o[j] = p[j] + bfc[j];
    }
}

static inline int cdiv(long long a, int b) { return (int)((a + b - 1) / b); }

extern "C" void kernel_launch(void* const* d_in, const int* in_sizes, int n_in,
                              void* d_out, int out_size, void* d_ws, size_t ws_size,
                              hipStream_t stream) {
    const float* x   = (const float*)d_in[0];
    const int*   ei  = (const int*)d_in[1];
    const float* W1  = (const float*)d_in[2];
    const float* b1  = (const float*)d_in[3];
    const float* W2  = (const float*)d_in[4];
    const float* b2  = (const float*)d_in[5];
    const float* Wfc = (const float*)d_in[6];
    const float* bfc = (const float*)d_in[7];
    float* out = (float*)d_out;

    const int N = in_sizes[0] / 128;   // 100000
    const int E = in_sizes[1] / 2;     // 1600000
    const int* src = ei;
    const int* dst = ei + E;

    char* ws = (char*)d_ws;
    size_t off = 0;
    auto alloc = [&](size_t bytes) { void* p = ws + off; off = (off + bytes + 255) & ~(size_t)255; return p; };
    float*    dinv    = (float*)   alloc((size_t)N * 4);
    int*      row_ptr = (int*)     alloc((size_t)(N + 1) * 4);
    int*      gcursor = (int*)     alloc((size_t)NB * 4);
    unsigned* ebuf    = (unsigned*)alloc((size_t)NB * BCAP * 4);
    int*      col     = (int*)     alloc((size_t)E * 4);
    __half*   Hh1     = (__half*)  alloc((size_t)N * 128 * 2);
    __half*   Ah1     = (__half*)  alloc((size_t)N * 128 * 2);
    __half*   Hh2     = (__half*)  alloc((size_t)N * 64 * 2);

    hipMemsetAsync(gcursor, 0, (size_t)NB * 4, stream);

    // bucket scatter (standalone)
    k_scatter<<<cdiv(E, CHUNK), 256, 0, stream>>>(src, dst, E, gcursor, ebuf);

    // {CSR build | MFMA GEMM1} fused 1:4 (grid NB*5 = 980; 784 gemm blocks cover 782)
    k_csr_gemm1<<<NB * 5, 256, 0, stream>>>(ebuf, gcursor, row_ptr, col, dinv, N,
                                            x, W1, Hh1, N);

    // layer 1 aggregate (dinv[src] folded into gather weights)
    k_gather128<<<cdiv(N, 4), 256, 0, stream>>>(Hh1, dinv, row_ptr, col, Ah1, N);

    // layer 2 transform (MFMA) then aggregate+FC (writes d_out directly)
    k_gemm2<<<cdiv(N, 128), 256, 0, stream>>>(Ah1, W2, b1, dinv, Hh2, N);
    k_gather_fc<<<cdiv(N, 4), 256, 0, stream>>>(Hh2, dinv, row_ptr, col,
                                                b2, Wfc, bfc, out, N);
}